// Round 1
// baseline (1012.665 us; speedup 1.0000x reference)
//
#include <hip/hip_runtime.h>

// Problem constants (from reference setup_inputs)
constexpr int NN  = 50000;   // nodes
constexpr int NE  = 400000;  // edges
constexpr int F0  = 128;     // input features
constexpr int F1  = 512;     // hidden features
constexpr int F2  = 250;     // output features
constexpr int F2P = 256;     // padded output stride for aligned float4

// ---------------- degree / norm ----------------
__global__ void k_init_deg(float* __restrict__ deg) {
    int i = blockIdx.x * 256 + threadIdx.x;
    if (i < NN) deg[i] = 1.0f;                 // self-loop
}
__global__ void k_count_deg(const int* __restrict__ dst, float* __restrict__ deg) {
    int e = blockIdx.x * 256 + threadIdx.x;
    if (e < NE) atomicAdd(&deg[dst[e]], 1.0f);
}
__global__ void k_dinv(float* __restrict__ deg) {
    int i = blockIdx.x * 256 + threadIdx.x;
    if (i < NN) deg[i] = rsqrtf(deg[i]);       // deg >= 1 always (self-loop)
}

// ---------------- layer 1: agg1 = A_norm * x  (aggregate-first, 128-dim) ----------------
__global__ void k_init_agg1(const float4* __restrict__ x4, const float* __restrict__ dinv,
                            float4* __restrict__ agg4) {
    int t = blockIdx.x * 256 + threadIdx.x;    // NN*32 float4s
    if (t >= NN * (F0 / 4)) return;
    int node = t >> 5;
    float s = dinv[node]; s = s * s;           // self-loop norm = dinv^2
    float4 v = x4[t];
    v.x *= s; v.y *= s; v.z *= s; v.w *= s;
    agg4[t] = v;
}
__global__ void k_scatter1(const int* __restrict__ ei, const float* __restrict__ dinv,
                           const float* __restrict__ x, float* __restrict__ agg1) {
    int e = blockIdx.x * 2 + (threadIdx.x >> 7);   // 2 edges per 256-thread block
    int c = threadIdx.x & 127;
    if (e >= NE) return;
    int s = ei[e], d = ei[NE + e];
    float nrm = dinv[s] * dinv[d];
    atomicAdd(&agg1[d * F0 + c], nrm * x[s * F0 + c]);
}

// ---------------- fp32 tiled GEMM: C[M,*] = A[M,K] @ B[K,*] (+bias, relu) ----------------
// BM=128, BN=64, BK=16, 256 threads, 8x4 accum per thread.
__global__ __launch_bounds__(256) void k_gemm_f32(
        const float* __restrict__ A, int lda,
        const float* __restrict__ B, int ldb,
        float* __restrict__ C, int ldc,
        const float* __restrict__ bias, int do_relu,
        int M, int K)
{
    __shared__ float Ast[16][132];   // [k][m], padded: transpose-store is 2-way (free)
    __shared__ float Bs[16][64];     // [k][n]

    const int tid = threadIdx.x;
    const int m0 = blockIdx.y * 128;
    const int n0 = blockIdx.x * 64;
    const int tx = tid & 15;         // col group (*4)
    const int ty = tid >> 4;         // row group (*8)
    const int ar = tid >> 1;         // 0..127 A-tile row
    const int ac = (tid & 1) * 8;    // 0 or 8 k-offset
    const int br = tid >> 4;         // 0..15 B-tile row
    const int bc = (tid & 15) * 4;

    float acc[8][4] = {};
    const bool avalid = (m0 + ar) < M;
    const float* Aptr = A + (size_t)(m0 + ar) * lda;

    for (int k0 = 0; k0 < K; k0 += 16) {
        float4 a0 = {0, 0, 0, 0}, a1 = {0, 0, 0, 0};
        if (avalid) {
            a0 = *(const float4*)(Aptr + k0 + ac);
            a1 = *(const float4*)(Aptr + k0 + ac + 4);
        }
        float4 bv = *(const float4*)(B + (size_t)(k0 + br) * ldb + n0 + bc);

        Ast[ac + 0][ar] = a0.x; Ast[ac + 1][ar] = a0.y;
        Ast[ac + 2][ar] = a0.z; Ast[ac + 3][ar] = a0.w;
        Ast[ac + 4][ar] = a1.x; Ast[ac + 5][ar] = a1.y;
        Ast[ac + 6][ar] = a1.z; Ast[ac + 7][ar] = a1.w;
        *(float4*)&Bs[br][bc] = bv;
        __syncthreads();

#pragma unroll
        for (int kk = 0; kk < 16; ++kk) {
            float4 alo = *(const float4*)&Ast[kk][ty * 8];
            float4 ahi = *(const float4*)&Ast[kk][ty * 8 + 4];
            float4 b   = *(const float4*)&Bs[kk][tx * 4];
            float as8[8] = {alo.x, alo.y, alo.z, alo.w, ahi.x, ahi.y, ahi.z, ahi.w};
            float bs4[4] = {b.x, b.y, b.z, b.w};
#pragma unroll
            for (int i = 0; i < 8; ++i)
#pragma unroll
                for (int j = 0; j < 4; ++j)
                    acc[i][j] += as8[i] * bs4[j];
        }
        __syncthreads();
    }

    float4 bvad = {0, 0, 0, 0};
    if (bias) bvad = *(const float4*)&bias[n0 + tx * 4];
#pragma unroll
    for (int i = 0; i < 8; ++i) {
        int row = m0 + ty * 8 + i;
        if (row < M) {
            float4 v;
            v.x = acc[i][0] + bvad.x; v.y = acc[i][1] + bvad.y;
            v.z = acc[i][2] + bvad.z; v.w = acc[i][3] + bvad.w;
            if (do_relu) {
                v.x = fmaxf(v.x, 0.f); v.y = fmaxf(v.y, 0.f);
                v.z = fmaxf(v.z, 0.f); v.w = fmaxf(v.w, 0.f);
            }
            *(float4*)&C[(size_t)row * ldc + n0 + tx * 4] = v;
        }
    }
}

// ---------------- layer 2 helpers ----------------
__global__ void k_pad_w2(const float* __restrict__ W2, float* __restrict__ W2p) {
    int t = blockIdx.x * 256 + threadIdx.x;    // F1*F2P
    int k = t >> 8, n = t & 255;
    W2p[t] = (n < F2) ? W2[k * F2 + n] : 0.0f;
}
__global__ void k_init_out(const float* __restrict__ t2, const float* __restrict__ dinv,
                           float* __restrict__ out) {
    int t = blockIdx.x * 256 + threadIdx.x;
    if (t >= NN * F2) return;
    int node = t / F2, c = t - node * F2;
    float s = dinv[node];
    out[t] = s * s * t2[node * F2P + c];       // self-loop contribution
}
__global__ void k_scatter2(const int* __restrict__ ei, const float* __restrict__ dinv,
                           const float* __restrict__ t2, float* __restrict__ out) {
    int e = blockIdx.x;                        // one edge per block
    int c = threadIdx.x;
    if (c >= F2) return;
    int s = ei[e], d = ei[NE + e];
    float nrm = dinv[s] * dinv[d];
    atomicAdd(&out[d * F2 + c], nrm * t2[s * F2P + c]);
}
__global__ void k_finalize(const float* __restrict__ b2, float* __restrict__ out) {
    int t = blockIdx.x * 256 + threadIdx.x;
    if (t >= NN * F2) return;
    int node = t / F2, c = t - node * F2;
    out[t] = fmaxf(out[t] + b2[c], 0.0f);
}

extern "C" void kernel_launch(void* const* d_in, const int* in_sizes, int n_in,
                              void* d_out, int out_size, void* d_ws, size_t ws_size,
                              hipStream_t stream) {
    const float* x  = (const float*)d_in[0];
    const int*   ei = (const int*)d_in[1];     // [2, NE]: first NE = src, next NE = dst
    const float* W1 = (const float*)d_in[2];
    const float* b1 = (const float*)d_in[3];
    const float* W2 = (const float*)d_in[4];
    const float* b2 = (const float*)d_in[5];
    float* out = (float*)d_out;

    // workspace layout (floats)
    float* ws   = (float*)d_ws;
    float* dinv = ws;                          //    50,176 (padded)
    float* agg1 = ws + 50176;                  // 6,400,000  [NN,128]
    float* h1   = agg1 + 6400000;              // 25,600,000 [NN,512]
    float* t2   = h1 + 25600000;               // 12,800,000 [NN,256 padded]
    float* w2p  = t2 + 12800000;               //   131,072  [512,256 padded]

    // norm coefficients
    k_init_deg <<<(NN + 255) / 256, 256, 0, stream>>>(dinv);
    k_count_deg<<<(NE + 255) / 256, 256, 0, stream>>>(ei + NE, dinv);
    k_dinv     <<<(NN + 255) / 256, 256, 0, stream>>>(dinv);

    // layer 1: aggregate-first (128-dim), then GEMM+bias+relu
    k_init_agg1<<<(NN * 32 + 255) / 256, 256, 0, stream>>>((const float4*)x, dinv, (float4*)agg1);
    k_scatter1 <<<NE / 2, 256, 0, stream>>>(ei, dinv, x, agg1);
    k_gemm_f32 <<<dim3(F1 / 64, (NN + 127) / 128), 256, 0, stream>>>(
        agg1, F0, W1, F1, h1, F1, b1, 1, NN, F0);

    // layer 2: GEMM-first (250-dim scatter), then aggregate + bias + relu
    k_pad_w2   <<<(F1 * F2P) / 256, 256, 0, stream>>>(W2, w2p);
    k_gemm_f32 <<<dim3(F2P / 64, (NN + 127) / 128), 256, 0, stream>>>(
        h1, F1, w2p, F2P, t2, F2P, nullptr, 0, NN, F1);
    k_init_out <<<(NN * F2 + 255) / 256, 256, 0, stream>>>(t2, dinv, out);
    k_scatter2 <<<NE, 256, 0, stream>>>(ei, dinv, t2, out);
    k_finalize <<<(NN * F2 + 255) / 256, 256, 0, stream>>>(b2, out);
}

// Round 2
// 601.174 us; speedup vs baseline: 1.6845x; 1.6845x over previous
//
#include <hip/hip_runtime.h>

// Problem constants (from reference setup_inputs)
constexpr int NN  = 50000;   // nodes
constexpr int NE  = 400000;  // edges
constexpr int F0  = 128;     // input features
constexpr int F1  = 512;     // hidden features
constexpr int F2  = 250;     // output features
constexpr int F2P = 256;     // padded output stride for aligned float4

// ================= CSR build (by dst) =================
__global__ void k_hist(const int* __restrict__ dst, int* __restrict__ cnt) {
    int e = blockIdx.x * 256 + threadIdx.x;
    if (e < NE) atomicAdd(&cnt[dst[e]], 1);
}

// single-block exclusive scan of cnt[NN] -> off[NN+1]
__global__ __launch_bounds__(1024) void k_scan(const int* __restrict__ cnt,
                                               int* __restrict__ off) {
    __shared__ int lds[1024];
    const int t = threadIdx.x;
    const int ITEMS = (NN + 1023) / 1024;      // 49
    const int base = t * ITEMS;
    int s = 0;
    for (int i = 0; i < ITEMS; ++i) {
        int idx = base + i;
        if (idx < NN) s += cnt[idx];
    }
    lds[t] = s;
    __syncthreads();
    for (int d = 1; d < 1024; d <<= 1) {
        int add = 0;
        if (t >= d) add = lds[t - d];
        __syncthreads();
        if (t >= d) lds[t] += add;
        __syncthreads();
    }
    int run = lds[t] - s;                      // exclusive prefix of this chunk
    for (int i = 0; i < ITEMS; ++i) {
        int idx = base + i;
        if (idx < NN) { off[idx] = run; run += cnt[idx]; }
    }
    if (t == 0) off[NN] = NE;
}

__global__ void k_bucket(const int* __restrict__ ei, const int* __restrict__ off,
                         int* __restrict__ cur, int* __restrict__ csr_src) {
    int e = blockIdx.x * 256 + threadIdx.x;
    if (e >= NE) return;
    int s = ei[e], d = ei[NE + e];
    int pos = off[d] + atomicAdd(&cur[d], 1);
    csr_src[pos] = s;
}

__global__ void k_dinv(const int* __restrict__ off, float* __restrict__ dinv) {
    int i = blockIdx.x * 256 + threadIdx.x;
    if (i < NN) dinv[i] = rsqrtf((float)(off[i + 1] - off[i]) + 1.0f);  // +1 self-loop
}

// ================= layer 1: gather-aggregate x (128-dim) =================
// agg1[n] = dinv[n] * ( dinv[n]*x[n] + sum_{s in in(n)} dinv[s]*x[s] )
__global__ __launch_bounds__(256) void k_gather1(
        const float4* __restrict__ x4, const int* __restrict__ off,
        const int* __restrict__ csr, const float* __restrict__ dinv,
        float4* __restrict__ agg4) {
    int n = blockIdx.x * 8 + (threadIdx.x >> 5);   // 8 nodes / block, 32 thr / node
    int c = threadIdx.x & 31;                      // float4 column
    if (n >= NN) return;
    float dn = dinv[n];
    float4 a = x4[(size_t)n * 32 + c];
    float4 acc = {a.x * dn, a.y * dn, a.z * dn, a.w * dn};
    int e1 = off[n + 1];
    for (int j = off[n]; j < e1; ++j) {
        int s = csr[j];
        float w = dinv[s];
        float4 v = x4[(size_t)s * 32 + c];
        acc.x += w * v.x; acc.y += w * v.y; acc.z += w * v.z; acc.w += w * v.w;
    }
    acc.x *= dn; acc.y *= dn; acc.z *= dn; acc.w *= dn;
    agg4[(size_t)n * 32 + c] = acc;
}

// ================= fp32 tiled GEMM (+bias, relu) =================
// BM=128, BN=64, BK=16, 256 threads, 8x4 accum per thread.
__global__ __launch_bounds__(256) void k_gemm_f32(
        const float* __restrict__ A, int lda,
        const float* __restrict__ B, int ldb,
        float* __restrict__ C, int ldc,
        const float* __restrict__ bias, int do_relu,
        int M, int K)
{
    __shared__ float Ast[16][132];   // [k][m], padded
    __shared__ float Bs[16][64];     // [k][n]

    const int tid = threadIdx.x;
    const int m0 = blockIdx.y * 128;
    const int n0 = blockIdx.x * 64;
    const int tx = tid & 15;
    const int ty = tid >> 4;
    const int ar = tid >> 1;
    const int ac = (tid & 1) * 8;
    const int br = tid >> 4;
    const int bc = (tid & 15) * 4;

    float acc[8][4] = {};
    const bool avalid = (m0 + ar) < M;
    const float* Aptr = A + (size_t)(m0 + ar) * lda;

    for (int k0 = 0; k0 < K; k0 += 16) {
        float4 a0 = {0, 0, 0, 0}, a1 = {0, 0, 0, 0};
        if (avalid) {
            a0 = *(const float4*)(Aptr + k0 + ac);
            a1 = *(const float4*)(Aptr + k0 + ac + 4);
        }
        float4 bv = *(const float4*)(B + (size_t)(k0 + br) * ldb + n0 + bc);

        Ast[ac + 0][ar] = a0.x; Ast[ac + 1][ar] = a0.y;
        Ast[ac + 2][ar] = a0.z; Ast[ac + 3][ar] = a0.w;
        Ast[ac + 4][ar] = a1.x; Ast[ac + 5][ar] = a1.y;
        Ast[ac + 6][ar] = a1.z; Ast[ac + 7][ar] = a1.w;
        *(float4*)&Bs[br][bc] = bv;
        __syncthreads();

#pragma unroll
        for (int kk = 0; kk < 16; ++kk) {
            float4 alo = *(const float4*)&Ast[kk][ty * 8];
            float4 ahi = *(const float4*)&Ast[kk][ty * 8 + 4];
            float4 b   = *(const float4*)&Bs[kk][tx * 4];
            float as8[8] = {alo.x, alo.y, alo.z, alo.w, ahi.x, ahi.y, ahi.z, ahi.w};
            float bs4[4] = {b.x, b.y, b.z, b.w};
#pragma unroll
            for (int i = 0; i < 8; ++i)
#pragma unroll
                for (int j = 0; j < 4; ++j)
                    acc[i][j] += as8[i] * bs4[j];
        }
        __syncthreads();
    }

    float4 bvad = {0, 0, 0, 0};
    if (bias) bvad = *(const float4*)&bias[n0 + tx * 4];
#pragma unroll
    for (int i = 0; i < 8; ++i) {
        int row = m0 + ty * 8 + i;
        if (row < M) {
            float4 v;
            v.x = acc[i][0] + bvad.x; v.y = acc[i][1] + bvad.y;
            v.z = acc[i][2] + bvad.z; v.w = acc[i][3] + bvad.w;
            if (do_relu) {
                v.x = fmaxf(v.x, 0.f); v.y = fmaxf(v.y, 0.f);
                v.z = fmaxf(v.z, 0.f); v.w = fmaxf(v.w, 0.f);
            }
            *(float4*)&C[(size_t)row * ldc + n0 + tx * 4] = v;
        }
    }
}

// ================= layer 2 helpers =================
__global__ void k_pad_w2(const float* __restrict__ W2, float* __restrict__ W2p) {
    int t = blockIdx.x * 256 + threadIdx.x;    // F1*F2P
    int k = t >> 8, n = t & 255;
    W2p[t] = (n < F2) ? W2[k * F2 + n] : 0.0f;
}

// out[n] = relu( dinv[n] * ( dinv[n]*t2[n] + sum dinv[s]*t2[s] ) + b2 )
__global__ __launch_bounds__(256) void k_gather2(
        const float4* __restrict__ t4, const int* __restrict__ off,
        const int* __restrict__ csr, const float* __restrict__ dinv,
        const float* __restrict__ b2, float* __restrict__ out) {
    int n = blockIdx.x * 4 + (threadIdx.x >> 6);   // 4 nodes / block, 64 thr / node
    int c = threadIdx.x & 63;                      // float4 column over 256-wide t2
    if (n >= NN) return;
    float dn = dinv[n];
    float4 a = t4[(size_t)n * 64 + c];
    float4 acc = {a.x * dn, a.y * dn, a.z * dn, a.w * dn};
    int e1 = off[n + 1];
    for (int j = off[n]; j < e1; ++j) {
        int s = csr[j];
        float w = dinv[s];
        float4 v = t4[(size_t)s * 64 + c];
        acc.x += w * v.x; acc.y += w * v.y; acc.z += w * v.z; acc.w += w * v.w;
    }
    int f = c * 4;
    float* o = out + (size_t)n * F2;
    if (f     < F2) o[f]     = fmaxf(dn * acc.x + b2[f],     0.f);
    if (f + 1 < F2) o[f + 1] = fmaxf(dn * acc.y + b2[f + 1], 0.f);
    if (f + 2 < F2) o[f + 2] = fmaxf(dn * acc.z + b2[f + 2], 0.f);
    if (f + 3 < F2) o[f + 3] = fmaxf(dn * acc.w + b2[f + 3], 0.f);
}

extern "C" void kernel_launch(void* const* d_in, const int* in_sizes, int n_in,
                              void* d_out, int out_size, void* d_ws, size_t ws_size,
                              hipStream_t stream) {
    const float* x  = (const float*)d_in[0];
    const int*   ei = (const int*)d_in[1];     // [2, NE]: first NE = src, next NE = dst
    const float* W1 = (const float*)d_in[2];
    const float* b1 = (const float*)d_in[3];
    const float* W2 = (const float*)d_in[4];
    const float* b2 = (const float*)d_in[5];
    float* out = (float*)d_out;

    // workspace layout (element offsets, 16B-aligned)
    float* ws   = (float*)d_ws;
    float* dinv = ws;                          //     50,176
    float* agg1 = ws + 50176;                  //  6,400,000  [NN,128]
    float* h1   = agg1 + 6400000;              // 25,600,000  [NN,512]
    float* t2   = h1 + 25600000;               // 12,800,000  [NN,256]
    float* w2p  = t2 + 12800000;               //    131,072  [512,256]
    int*   cnt  = (int*)(w2p + 131072);        //     50,176
    int*   off  = cnt + 50176;                 //     50,432  (NN+1)
    int*   cur  = off + 50432;                 //     50,176
    int*   csr  = cur + 50176;                 //    400,000

    // ---- CSR build (by dst) + norm ----
    hipMemsetAsync(cnt, 0, NN * sizeof(int), stream);
    hipMemsetAsync(cur, 0, NN * sizeof(int), stream);
    k_hist  <<<(NE + 255) / 256, 256, 0, stream>>>(ei + NE, cnt);
    k_scan  <<<1, 1024, 0, stream>>>(cnt, off);
    k_bucket<<<(NE + 255) / 256, 256, 0, stream>>>(ei, off, cur, csr);
    k_dinv  <<<(NN + 255) / 256, 256, 0, stream>>>(off, dinv);

    // ---- layer 1: aggregate-first (128-dim gather), then GEMM+bias+relu ----
    k_gather1<<<(NN + 7) / 8, 256, 0, stream>>>((const float4*)x, off, csr, dinv,
                                                (float4*)agg1);
    k_gemm_f32<<<dim3(F1 / 64, (NN + 127) / 128), 256, 0, stream>>>(
        agg1, F0, W1, F1, h1, F1, b1, 1, NN, F0);

    // ---- layer 2: GEMM-first, then gather + bias + relu ----
    k_pad_w2<<<(F1 * F2P) / 256, 256, 0, stream>>>(W2, w2p);
    k_gemm_f32<<<dim3(F2P / 64, (NN + 127) / 128), 256, 0, stream>>>(
        h1, F1, w2p, F2P, t2, F2P, nullptr, 0, NN, F1);
    k_gather2<<<(NN + 3) / 4, 256, 0, stream>>>((const float4*)t2, off, csr, dinv,
                                                b2, out);
}

// Round 3
// 409.039 us; speedup vs baseline: 2.4757x; 1.4697x over previous
//
#include <hip/hip_runtime.h>

// Problem constants
constexpr int NN  = 50000;   // nodes
constexpr int NE  = 400000;  // edges
constexpr int F0  = 128;     // input features
constexpr int F1  = 512;     // hidden features
constexpr int F2  = 250;     // output features
constexpr int MT  = 391;     // M tiles of 128 (391*128 = 50048)

typedef short  short8 __attribute__((ext_vector_type(8)));
typedef float  f32x4  __attribute__((ext_vector_type(4)));

__device__ inline unsigned short f2bf(float f) {
    union { float f; unsigned u; } v; v.f = f;
    unsigned u = v.u;
    return (unsigned short)((u + 0x7FFFu + ((u >> 16) & 1u)) >> 16);   // RNE
}
__device__ inline float bf2f(unsigned short h) {
    union { unsigned u; float f; } v; v.u = ((unsigned)h) << 16;
    return v.f;
}

// ================= CSR build (by dst) =================
__global__ void k_hist(const int* __restrict__ dst, int* __restrict__ cnt) {
    int e = blockIdx.x * 256 + threadIdx.x;
    if (e < NE) atomicAdd(&cnt[dst[e]], 1);
}

__global__ __launch_bounds__(1024) void k_scan(const int* __restrict__ cnt,
                                               int* __restrict__ off) {
    __shared__ int lds[1024];
    const int t = threadIdx.x;
    const int ITEMS = (NN + 1023) / 1024;      // 49
    const int base = t * ITEMS;
    int s = 0;
    for (int i = 0; i < ITEMS; ++i) {
        int idx = base + i;
        if (idx < NN) s += cnt[idx];
    }
    lds[t] = s;
    __syncthreads();
    for (int d = 1; d < 1024; d <<= 1) {
        int add = 0;
        if (t >= d) add = lds[t - d];
        __syncthreads();
        if (t >= d) lds[t] += add;
        __syncthreads();
    }
    int run = lds[t] - s;
    for (int i = 0; i < ITEMS; ++i) {
        int idx = base + i;
        if (idx < NN) { off[idx] = run; run += cnt[idx]; }
    }
    if (t == 0) off[NN] = NE;
}

__global__ void k_bucket(const int* __restrict__ ei, const int* __restrict__ off,
                         int* __restrict__ cur, int* __restrict__ csr_src) {
    int e = blockIdx.x * 256 + threadIdx.x;
    if (e >= NE) return;
    int s = ei[e], d = ei[NE + e];
    int pos = off[d] + atomicAdd(&cur[d], 1);
    csr_src[pos] = s;
}

__global__ void k_dinv(const int* __restrict__ off, float* __restrict__ dinv) {
    int i = blockIdx.x * 256 + threadIdx.x;
    if (i < NN) dinv[i] = rsqrtf((float)(off[i + 1] - off[i]) + 1.0f);  // +1 self-loop
}

// ================= dtype prep =================
__global__ void k_xbf(const float4* __restrict__ x4, ushort4* __restrict__ xb) {
    int t = blockIdx.x * 256 + threadIdx.x;       // NN*32
    if (t >= NN * 32) return;
    float4 v = x4[t];
    ushort4 o; o.x = f2bf(v.x); o.y = f2bf(v.y); o.z = f2bf(v.z); o.w = f2bf(v.w);
    xb[t] = o;
}
// W1 [128,512] fp32 -> W1t [512,128] bf16
__global__ void k_w1t(const float* __restrict__ W1, unsigned short* __restrict__ W1t) {
    int t = blockIdx.x * 256 + threadIdx.x;       // 512*128
    if (t >= F1 * F0) return;
    int n = t >> 7, k = t & 127;
    W1t[t] = f2bf(W1[k * F1 + n]);
}
// W2 [512,250] fp32 -> W2t [256,512] bf16, rows >=250 zero
__global__ void k_w2t(const float* __restrict__ W2, unsigned short* __restrict__ W2t) {
    int t = blockIdx.x * 256 + threadIdx.x;       // 256*512
    if (t >= 256 * F1) return;
    int n = t >> 9, k = t & 511;
    W2t[t] = (n < F2) ? f2bf(W2[k * F2 + n]) : (unsigned short)0;
}

// ================= gathers (CSR, no atomics) =================
// agg1[n] = bf16( dinv[n] * ( dinv[n]*x[n] + sum dinv[s]*x[s] ) )   128-dim
__global__ __launch_bounds__(256) void k_gather1(
        const ushort4* __restrict__ xb, const int* __restrict__ off,
        const int* __restrict__ csr, const float* __restrict__ dinv,
        ushort4* __restrict__ agg) {
    int n = blockIdx.x * 8 + (threadIdx.x >> 5);
    int c = threadIdx.x & 31;
    if (n >= NN) return;
    float dn = dinv[n];
    ushort4 a = xb[(size_t)n * 32 + c];
    float ax = bf2f(a.x), ay = bf2f(a.y), az = bf2f(a.z), aw = bf2f(a.w);
    float sx = dn * ax, sy = dn * ay, sz = dn * az, sw = dn * aw;
    int e1 = off[n + 1];
    for (int j = off[n]; j < e1; ++j) {
        int s = csr[j];
        float w = dinv[s];
        ushort4 v = xb[(size_t)s * 32 + c];
        sx += w * bf2f(v.x); sy += w * bf2f(v.y);
        sz += w * bf2f(v.z); sw += w * bf2f(v.w);
    }
    ushort4 o;
    o.x = f2bf(dn * sx); o.y = f2bf(dn * sy); o.z = f2bf(dn * sz); o.w = f2bf(dn * sw);
    agg[(size_t)n * 32 + c] = o;
}

// out[n] = relu( dinv[n]*( dinv[n]*t2[n] + sum dinv[s]*t2[s] ) + b2 )  250-dim fp32
__global__ __launch_bounds__(256) void k_gather2(
        const ushort4* __restrict__ t4, const int* __restrict__ off,
        const int* __restrict__ csr, const float* __restrict__ dinv,
        const float* __restrict__ b2, float* __restrict__ out) {
    int n = blockIdx.x * 4 + (threadIdx.x >> 6);
    int c = threadIdx.x & 63;                     // 4 bf16 per thread over 256 cols
    if (n >= NN) return;
    float dn = dinv[n];
    ushort4 a = t4[(size_t)n * 64 + c];
    float sx = dn * bf2f(a.x), sy = dn * bf2f(a.y);
    float sz = dn * bf2f(a.z), sw = dn * bf2f(a.w);
    int e1 = off[n + 1];
    for (int j = off[n]; j < e1; ++j) {
        int s = csr[j];
        float w = dinv[s];
        ushort4 v = t4[(size_t)s * 64 + c];
        sx += w * bf2f(v.x); sy += w * bf2f(v.y);
        sz += w * bf2f(v.z); sw += w * bf2f(v.w);
    }
    int f = c * 4;
    float* o = out + (size_t)n * F2;
    if (f     < F2) o[f]     = fmaxf(dn * sx + b2[f],     0.f);
    if (f + 1 < F2) o[f + 1] = fmaxf(dn * sy + b2[f + 1], 0.f);
    if (f + 2 < F2) o[f + 2] = fmaxf(dn * sz + b2[f + 2], 0.f);
    if (f + 3 < F2) o[f + 3] = fmaxf(dn * sw + b2[f + 3], 0.f);
}

// ================= bf16 MFMA GEMM: C = A[M,K] * Bt[N,K]^T (+bias,relu) =================
// 128x128 tile, BK=32, 4 waves (2x2), each wave 64x64 via 4x4 frags of 16x16x32.
// LDS slot-swizzle: chunk q of row m stored at slot q ^ ((m>>1)&3) -> frag reads 2-way (free).
__global__ __launch_bounds__(256) void k_gemm_bf16(
        const unsigned short* __restrict__ A, int lda,
        const unsigned short* __restrict__ Bt, int ldb,
        unsigned short* __restrict__ C, int ldc,
        const float* __restrict__ bias, int do_relu,
        int M, int K)
{
    __shared__ unsigned short As[128 * 32];   // 8 KB
    __shared__ unsigned short Bs[128 * 32];   // 8 KB

    const int tid = threadIdx.x;
    const int wv = tid >> 6, ln = tid & 63;
    const int m0 = blockIdx.y * 128, n0 = blockIdx.x * 128;
    const int wy = wv >> 1, wx = wv & 1;
    const int lane15 = ln & 15, quad = ln >> 4;

    // staging pointers: chunk c = (i*4+wv)*64 + ln covers (row m = c>>2, slot q = c&3)
    const unsigned short* ag[2];
    const unsigned short* bg[2];
    int ldsoff[2];
#pragma unroll
    for (int i = 0; i < 2; ++i) {
        int c = (i * 4 + wv) * 64 + ln;
        int m = c >> 2, q = c & 3;
        int gq = q ^ ((m >> 1) & 3);          // which global 8-elem chunk lands here
        int arow = m0 + m; if (arow > M - 1) arow = M - 1;   // clamp tail tile
        ag[i] = A  + (size_t)arow * lda + gq * 8;
        bg[i] = Bt + (size_t)(n0 + m) * ldb + gq * 8;
        ldsoff[i] = (i * 4 + wv) * 512;       // elements; wave-uniform
    }

    f32x4 acc[4][4];
#pragma unroll
    for (int fy = 0; fy < 4; ++fy)
#pragma unroll
        for (int fx = 0; fx < 4; ++fx)
            acc[fy][fx] = (f32x4)0.0f;

    for (int k0 = 0; k0 < K; k0 += 32) {
#pragma unroll
        for (int i = 0; i < 2; ++i) {
            __builtin_amdgcn_global_load_lds(
                (const __attribute__((address_space(1))) void*)ag[i],
                (__attribute__((address_space(3))) void*)(As + ldsoff[i]), 16, 0, 0);
            __builtin_amdgcn_global_load_lds(
                (const __attribute__((address_space(1))) void*)bg[i],
                (__attribute__((address_space(3))) void*)(Bs + ldsoff[i]), 16, 0, 0);
            ag[i] += 32; bg[i] += 32;
        }
        __syncthreads();

        short8 af[4], bf[4];
#pragma unroll
        for (int f = 0; f < 4; ++f) {
            int mA = wy * 64 + f * 16 + lane15;
            int sA = quad ^ ((mA >> 1) & 3);
            af[f] = *(const short8*)(As + mA * 32 + sA * 8);
            int nB = wx * 64 + f * 16 + lane15;
            int sB = quad ^ ((nB >> 1) & 3);
            bf[f] = *(const short8*)(Bs + nB * 32 + sB * 8);
        }
#pragma unroll
        for (int fy = 0; fy < 4; ++fy)
#pragma unroll
            for (int fx = 0; fx < 4; ++fx)
                acc[fy][fx] = __builtin_amdgcn_mfma_f32_16x16x32_bf16(
                    af[fy], bf[fx], acc[fy][fx], 0, 0, 0);
        __syncthreads();
    }

    // epilogue: C/D layout col=lane&15, row=quad*4+reg (m89-verified)
#pragma unroll
    for (int fy = 0; fy < 4; ++fy) {
        int rowb = m0 + wy * 64 + fy * 16 + quad * 4;
#pragma unroll
        for (int fx = 0; fx < 4; ++fx) {
            int col = n0 + wx * 64 + fx * 16 + lane15;
            float bia = bias ? bias[col] : 0.0f;
            f32x4 v = acc[fy][fx];
#pragma unroll
            for (int r = 0; r < 4; ++r) {
                int row = rowb + r;
                if (row < M) {
                    float val = v[r] + bia;
                    if (do_relu) val = fmaxf(val, 0.0f);
                    C[(size_t)row * ldc + col] = f2bf(val);
                }
            }
        }
    }
}

extern "C" void kernel_launch(void* const* d_in, const int* in_sizes, int n_in,
                              void* d_out, int out_size, void* d_ws, size_t ws_size,
                              hipStream_t stream) {
    const float* x  = (const float*)d_in[0];
    const int*   ei = (const int*)d_in[1];
    const float* W1 = (const float*)d_in[2];
    const float* b1 = (const float*)d_in[3];
    const float* W2 = (const float*)d_in[4];
    const float* b2 = (const float*)d_in[5];
    float* out = (float*)d_out;

    // workspace carve (256 B aligned)
    char* p = (char*)d_ws;
    auto carve = [&](size_t bytes) { char* r = p; p += (bytes + 255) & ~(size_t)255; return r; };
    float*          dinv = (float*)carve(NN * 4);
    int*            cnt  = (int*)carve(NN * 4);
    int*            off  = (int*)carve((NN + 1) * 4);
    int*            cur  = (int*)carve(NN * 4);
    int*            csr  = (int*)carve(NE * 4);
    unsigned short* xb   = (unsigned short*)carve((size_t)NN * F0 * 2);
    unsigned short* agg1 = (unsigned short*)carve((size_t)NN * F0 * 2);
    unsigned short* h1   = (unsigned short*)carve((size_t)NN * F1 * 2);
    unsigned short* t2   = (unsigned short*)carve((size_t)NN * 256 * 2);
    unsigned short* w1t  = (unsigned short*)carve((size_t)F1 * F0 * 2);
    unsigned short* w2t  = (unsigned short*)carve((size_t)256 * F1 * 2);

    // CSR + norm
    hipMemsetAsync(cnt, 0, NN * sizeof(int), stream);
    hipMemsetAsync(cur, 0, NN * sizeof(int), stream);
    k_hist  <<<(NE + 255) / 256, 256, 0, stream>>>(ei + NE, cnt);
    k_scan  <<<1, 1024, 0, stream>>>(cnt, off);
    k_bucket<<<(NE + 255) / 256, 256, 0, stream>>>(ei, off, cur, csr);
    k_dinv  <<<(NN + 255) / 256, 256, 0, stream>>>(off, dinv);

    // dtype prep
    k_xbf<<<(NN * 32 + 255) / 256, 256, 0, stream>>>((const float4*)x, (ushort4*)xb);
    k_w1t<<<(F1 * F0 + 255) / 256, 256, 0, stream>>>(W1, w1t);
    k_w2t<<<(256 * F1 + 255) / 256, 256, 0, stream>>>(W2, w2t);

    // layer 1: aggregate (128-dim) then MFMA GEMM + bias + relu -> h1 bf16
    k_gather1<<<(NN + 7) / 8, 256, 0, stream>>>((const ushort4*)xb, off, csr, dinv,
                                                (ushort4*)agg1);
    k_gemm_bf16<<<dim3(F1 / 128, MT), 256, 0, stream>>>(
        agg1, F0, w1t, F0, h1, F1, b1, 1, NN, F0);

    // layer 2: MFMA GEMM -> t2 bf16 (256-wide, cols 250+ zero), then gather + bias + relu
    k_gemm_bf16<<<dim3(256 / 128, MT), 256, 0, stream>>>(
        h1, F1, w2t, F1, t2, 256, nullptr, 0, NN, F1);
    k_gather2<<<(NN + 3) / 4, 256, 0, stream>>>((const ushort4*)t2, off, csr, dinv,
                                                b2, out);
}

// Round 4
// 324.329 us; speedup vs baseline: 3.1223x; 1.2612x over previous
//
#include <hip/hip_runtime.h>

// Problem constants
constexpr int NN  = 50000;   // nodes
constexpr int NE  = 400000;  // edges
constexpr int F0  = 128;     // input features
constexpr int F1  = 512;     // hidden features
constexpr int F2  = 250;     // output features
constexpr int MT  = 391;     // M tiles of 128 (391*128 = 50048)
constexpr int SCAN_N = 50176;    // 49 * 1024, padded count array
constexpr int SCAN_B = 49;       // scan blocks (1024 elems each)

typedef short  short8 __attribute__((ext_vector_type(8)));
typedef float  f32x4  __attribute__((ext_vector_type(4)));

__device__ inline unsigned short f2bf(float f) {
    union { float f; unsigned u; } v; v.f = f;
    unsigned u = v.u;
    return (unsigned short)((u + 0x7FFFu + ((u >> 16) & 1u)) >> 16);   // RNE
}
__device__ inline float bf2f(unsigned short h) {
    union { unsigned u; float f; } v; v.u = ((unsigned)h) << 16;
    return v.f;
}

// ================= CSR build (by dst) =================
__global__ void k_hist(const int* __restrict__ dst, int* __restrict__ cnt) {
    int e = blockIdx.x * 256 + threadIdx.x;
    if (e < NE) atomicAdd(&cnt[dst[e]], 1);
}

// --- hierarchical exclusive scan of cnt[SCAN_N] -> off[NN+1] ---
// A: per-block (1024 elems) totals
__global__ __launch_bounds__(256) void k_scanA(const int4* __restrict__ cnt4,
                                               int* __restrict__ bsum) {
    __shared__ int lds[256];
    const int b = blockIdx.x, t = threadIdx.x;
    int4 c = cnt4[b * 256 + t];
    lds[t] = c.x + c.y + c.z + c.w;
    __syncthreads();
    for (int d = 128; d > 0; d >>= 1) {
        if (t < d) lds[t] += lds[t + d];
        __syncthreads();
    }
    if (t == 0) bsum[b] = lds[0];
}
// B: scan the 49 block sums (single wave)
__global__ void k_scanB(const int* __restrict__ bsum, int* __restrict__ boff) {
    int t = threadIdx.x;                       // 64
    int v = (t < SCAN_B) ? bsum[t] : 0;
    int orig = v;
    for (int d = 1; d < 64; d <<= 1) {
        int u = __shfl_up(v, d);
        if (t >= d) v += u;
    }
    if (t < SCAN_B) boff[t] = v - orig;        // exclusive
}
// C: intra-block exclusive scan + block offset -> off[]
__global__ __launch_bounds__(256) void k_scanC(const int4* __restrict__ cnt4,
                                               const int* __restrict__ boff,
                                               int* __restrict__ off) {
    __shared__ int lds[256];
    const int b = blockIdx.x, t = threadIdx.x;
    int4 c = cnt4[b * 256 + t];
    int s = c.x + c.y + c.z + c.w;
    lds[t] = s;
    __syncthreads();
    for (int d = 1; d < 256; d <<= 1) {
        int add = (t >= d) ? lds[t - d] : 0;
        __syncthreads();
        lds[t] += add;
        __syncthreads();
    }
    int run = boff[b] + lds[t] - s;            // exclusive prefix at first elem
    int base = b * 1024 + t * 4;
    if (base     < NN) off[base]     = run;  run += c.x;
    if (base + 1 < NN) off[base + 1] = run;  run += c.y;
    if (base + 2 < NN) off[base + 2] = run;  run += c.z;
    if (base + 3 < NN) off[base + 3] = run;
    if (b == 0 && t == 0) off[NN] = NE;
}

__global__ void k_bucket(const int* __restrict__ ei, const int* __restrict__ off,
                         int* __restrict__ cur, int* __restrict__ csr_src) {
    int e = blockIdx.x * 256 + threadIdx.x;
    if (e >= NE) return;
    int s = ei[e], d = ei[NE + e];
    int pos = off[d] + atomicAdd(&cur[d], 1);
    csr_src[pos] = s;
}

__global__ void k_dinv(const int* __restrict__ off, float* __restrict__ dinv) {
    int i = blockIdx.x * 256 + threadIdx.x;
    if (i < NN) dinv[i] = rsqrtf((float)(off[i + 1] - off[i]) + 1.0f);  // +1 self-loop
}

// ================= dtype prep =================
__global__ void k_xbf(const float4* __restrict__ x4, ushort4* __restrict__ xb) {
    int t = blockIdx.x * 256 + threadIdx.x;       // NN*32
    if (t >= NN * 32) return;
    float4 v = x4[t];
    ushort4 o; o.x = f2bf(v.x); o.y = f2bf(v.y); o.z = f2bf(v.z); o.w = f2bf(v.w);
    xb[t] = o;
}
// W1 [128,512] fp32 -> W1t [512,128] bf16
__global__ void k_w1t(const float* __restrict__ W1, unsigned short* __restrict__ W1t) {
    int t = blockIdx.x * 256 + threadIdx.x;       // 512*128
    if (t >= F1 * F0) return;
    int n = t >> 7, k = t & 127;
    W1t[t] = f2bf(W1[k * F1 + n]);
}
// W2 [512,250] fp32 -> W2t [256,512] bf16, rows >=250 zero
__global__ void k_w2t(const float* __restrict__ W2, unsigned short* __restrict__ W2t) {
    int t = blockIdx.x * 256 + threadIdx.x;       // 256*512
    if (t >= 256 * F1) return;
    int n = t >> 9, k = t & 511;
    W2t[t] = (n < F2) ? f2bf(W2[k * F2 + n]) : (unsigned short)0;
}

// ================= gathers (CSR, no atomics) =================
// agg1[n] = bf16( dinv[n] * ( dinv[n]*x[n] + sum dinv[s]*x[s] ) )   128-dim
__global__ __launch_bounds__(256) void k_gather1(
        const ushort4* __restrict__ xb, const int* __restrict__ off,
        const int* __restrict__ csr, const float* __restrict__ dinv,
        ushort4* __restrict__ agg) {
    int n = blockIdx.x * 8 + (threadIdx.x >> 5);
    int c = threadIdx.x & 31;
    if (n >= NN) return;
    float dn = dinv[n];
    ushort4 a = xb[(size_t)n * 32 + c];
    float sx = dn * bf2f(a.x), sy = dn * bf2f(a.y);
    float sz = dn * bf2f(a.z), sw = dn * bf2f(a.w);
    int e1 = off[n + 1];
    for (int j = off[n]; j < e1; ++j) {
        int s = csr[j];
        float w = dinv[s];
        ushort4 v = xb[(size_t)s * 32 + c];
        sx += w * bf2f(v.x); sy += w * bf2f(v.y);
        sz += w * bf2f(v.z); sw += w * bf2f(v.w);
    }
    ushort4 o;
    o.x = f2bf(dn * sx); o.y = f2bf(dn * sy); o.z = f2bf(dn * sz); o.w = f2bf(dn * sw);
    agg[(size_t)n * 32 + c] = o;
}

// out[n] = relu( dinv[n]*( dinv[n]*t2[n] + sum dinv[s]*t2[s] ) + b2 )  250-dim fp32
__global__ __launch_bounds__(256) void k_gather2(
        const ushort4* __restrict__ t4, const int* __restrict__ off,
        const int* __restrict__ csr, const float* __restrict__ dinv,
        const float* __restrict__ b2, float* __restrict__ out) {
    int n = blockIdx.x * 4 + (threadIdx.x >> 6);
    int c = threadIdx.x & 63;                     // 4 bf16 per thread over 256 cols
    if (n >= NN) return;
    float dn = dinv[n];
    ushort4 a = t4[(size_t)n * 64 + c];
    float sx = dn * bf2f(a.x), sy = dn * bf2f(a.y);
    float sz = dn * bf2f(a.z), sw = dn * bf2f(a.w);
    int e1 = off[n + 1];
    for (int j = off[n]; j < e1; ++j) {
        int s = csr[j];
        float w = dinv[s];
        ushort4 v = t4[(size_t)s * 64 + c];
        sx += w * bf2f(v.x); sy += w * bf2f(v.y);
        sz += w * bf2f(v.z); sw += w * bf2f(v.w);
    }
    int f = c * 4;
    float* o = out + (size_t)n * F2;
    if (f     < F2) o[f]     = fmaxf(dn * sx + b2[f],     0.f);
    if (f + 1 < F2) o[f + 1] = fmaxf(dn * sy + b2[f + 1], 0.f);
    if (f + 2 < F2) o[f + 2] = fmaxf(dn * sz + b2[f + 2], 0.f);
    if (f + 3 < F2) o[f + 3] = fmaxf(dn * sw + b2[f + 3], 0.f);
}

// ================= bf16 MFMA GEMM: C = A[M,K] * Bt[N,K]^T (+bias,relu) =================
// 128x128 tile, BK=32, 4 waves (2x2), each wave 64x64 via 4x4 frags of 16x16x32.
// LDS slot-swizzle: chunk q of row m stored at slot q ^ ((m>>1)&3) -> frag reads 2-way (free).
__global__ __launch_bounds__(256) void k_gemm_bf16(
        const unsigned short* __restrict__ A, int lda,
        const unsigned short* __restrict__ Bt, int ldb,
        unsigned short* __restrict__ C, int ldc,
        const float* __restrict__ bias, int do_relu,
        int M, int K)
{
    __shared__ unsigned short As[128 * 32];   // 8 KB
    __shared__ unsigned short Bs[128 * 32];   // 8 KB

    const int tid = threadIdx.x;
    const int wv = tid >> 6, ln = tid & 63;
    const int m0 = blockIdx.y * 128, n0 = blockIdx.x * 128;
    const int wy = wv >> 1, wx = wv & 1;
    const int lane15 = ln & 15, quad = ln >> 4;

    const unsigned short* ag[2];
    const unsigned short* bg[2];
    int ldsoff[2];
#pragma unroll
    for (int i = 0; i < 2; ++i) {
        int c = (i * 4 + wv) * 64 + ln;
        int m = c >> 2, q = c & 3;
        int gq = q ^ ((m >> 1) & 3);          // which global 8-elem chunk lands here
        int arow = m0 + m; if (arow > M - 1) arow = M - 1;   // clamp tail tile
        ag[i] = A  + (size_t)arow * lda + gq * 8;
        bg[i] = Bt + (size_t)(n0 + m) * ldb + gq * 8;
        ldsoff[i] = (i * 4 + wv) * 512;       // elements; wave-uniform
    }

    f32x4 acc[4][4];
#pragma unroll
    for (int fy = 0; fy < 4; ++fy)
#pragma unroll
        for (int fx = 0; fx < 4; ++fx)
            acc[fy][fx] = (f32x4)0.0f;

    for (int k0 = 0; k0 < K; k0 += 32) {
#pragma unroll
        for (int i = 0; i < 2; ++i) {
            __builtin_amdgcn_global_load_lds(
                (const __attribute__((address_space(1))) void*)ag[i],
                (__attribute__((address_space(3))) void*)(As + ldsoff[i]), 16, 0, 0);
            __builtin_amdgcn_global_load_lds(
                (const __attribute__((address_space(1))) void*)bg[i],
                (__attribute__((address_space(3))) void*)(Bs + ldsoff[i]), 16, 0, 0);
            ag[i] += 32; bg[i] += 32;
        }
        __syncthreads();

        short8 af[4], bf[4];
#pragma unroll
        for (int f = 0; f < 4; ++f) {
            int mA = wy * 64 + f * 16 + lane15;
            int sA = quad ^ ((mA >> 1) & 3);
            af[f] = *(const short8*)(As + mA * 32 + sA * 8);
            int nB = wx * 64 + f * 16 + lane15;
            int sB = quad ^ ((nB >> 1) & 3);
            bf[f] = *(const short8*)(Bs + nB * 32 + sB * 8);
        }
#pragma unroll
        for (int fy = 0; fy < 4; ++fy)
#pragma unroll
            for (int fx = 0; fx < 4; ++fx)
                acc[fy][fx] = __builtin_amdgcn_mfma_f32_16x16x32_bf16(
                    af[fy], bf[fx], acc[fy][fx], 0, 0, 0);
        __syncthreads();
    }

    // epilogue: C/D layout col=lane&15, row=quad*4+reg (m89-verified)
#pragma unroll
    for (int fy = 0; fy < 4; ++fy) {
        int rowb = m0 + wy * 64 + fy * 16 + quad * 4;
#pragma unroll
        for (int fx = 0; fx < 4; ++fx) {
            int col = n0 + wx * 64 + fx * 16 + lane15;
            float bia = bias ? bias[col] : 0.0f;
            f32x4 v = acc[fy][fx];
#pragma unroll
            for (int r = 0; r < 4; ++r) {
                int row = rowb + r;
                if (row < M) {
                    float val = v[r] + bia;
                    if (do_relu) val = fmaxf(val, 0.0f);
                    C[(size_t)row * ldc + col] = f2bf(val);
                }
            }
        }
    }
}

extern "C" void kernel_launch(void* const* d_in, const int* in_sizes, int n_in,
                              void* d_out, int out_size, void* d_ws, size_t ws_size,
                              hipStream_t stream) {
    const float* x  = (const float*)d_in[0];
    const int*   ei = (const int*)d_in[1];
    const float* W1 = (const float*)d_in[2];
    const float* b1 = (const float*)d_in[3];
    const float* W2 = (const float*)d_in[4];
    const float* b2 = (const float*)d_in[5];
    float* out = (float*)d_out;

    // workspace carve (256 B aligned)
    char* p = (char*)d_ws;
    auto carve = [&](size_t bytes) { char* r = p; p += (bytes + 255) & ~(size_t)255; return r; };
    float*          dinv = (float*)carve(NN * 4);
    int*            cnt  = (int*)carve(SCAN_N * 4);
    int*            off  = (int*)carve((NN + 1) * 4);
    int*            cur  = (int*)carve(NN * 4);
    int*            csr  = (int*)carve(NE * 4);
    int*            bsum = (int*)carve(64 * 4);
    int*            boff = (int*)carve(64 * 4);
    unsigned short* xb   = (unsigned short*)carve((size_t)NN * F0 * 2);
    unsigned short* agg1 = (unsigned short*)carve((size_t)NN * F0 * 2);
    unsigned short* h1   = (unsigned short*)carve((size_t)NN * F1 * 2);
    unsigned short* t2   = (unsigned short*)carve((size_t)NN * 256 * 2);
    unsigned short* w1t  = (unsigned short*)carve((size_t)F1 * F0 * 2);
    unsigned short* w2t  = (unsigned short*)carve((size_t)256 * F1 * 2);

    // CSR + norm (hierarchical scan)
    hipMemsetAsync(cnt, 0, SCAN_N * sizeof(int), stream);
    hipMemsetAsync(cur, 0, NN * sizeof(int), stream);
    k_hist <<<(NE + 255) / 256, 256, 0, stream>>>(ei + NE, cnt);
    k_scanA<<<SCAN_B, 256, 0, stream>>>((const int4*)cnt, bsum);
    k_scanB<<<1, 64, 0, stream>>>(bsum, boff);
    k_scanC<<<SCAN_B, 256, 0, stream>>>((const int4*)cnt, boff, off);
    k_bucket<<<(NE + 255) / 256, 256, 0, stream>>>(ei, off, cur, csr);
    k_dinv <<<(NN + 255) / 256, 256, 0, stream>>>(off, dinv);

    // dtype prep
    k_xbf<<<(NN * 32 + 255) / 256, 256, 0, stream>>>((const float4*)x, (ushort4*)xb);
    k_w1t<<<(F1 * F0 + 255) / 256, 256, 0, stream>>>(W1, w1t);
    k_w2t<<<(256 * F1 + 255) / 256, 256, 0, stream>>>(W2, w2t);

    // layer 1: aggregate (128-dim) then MFMA GEMM + bias + relu -> h1 bf16
    k_gather1<<<(NN + 7) / 8, 256, 0, stream>>>((const ushort4*)xb, off, csr, dinv,
                                                (ushort4*)agg1);
    k_gemm_bf16<<<dim3(F1 / 128, MT), 256, 0, stream>>>(
        agg1, F0, w1t, F0, h1, F1, b1, 1, NN, F0);

    // layer 2: MFMA GEMM -> t2 bf16 (256-wide, cols 250+ zero), then gather + bias + relu
    k_gemm_bf16<<<dim3(256 / 128, MT), 256, 0, stream>>>(
        h1, F1, w2t, F1, t2, 256, nullptr, 0, NN, F1);
    k_gather2<<<(NN + 3) / 4, 256, 0, stream>>>((const ushort4*)t2, off, csr, dinv,
                                                b2, out);
}

// Round 5
// 292.090 us; speedup vs baseline: 3.4670x; 1.1104x over previous
//
#include <hip/hip_runtime.h>

// Problem constants
constexpr int NN  = 50000;   // nodes
constexpr int NE  = 400000;  // edges
constexpr int F0  = 128;     // input features
constexpr int F1  = 512;     // hidden features
constexpr int F2  = 250;     // output features
constexpr int MT  = 391;     // M tiles of 128 (391*128 = 50048)
constexpr int SCAN_N = 50176;    // 49 * 1024, padded count array
constexpr int SCAN_B = 49;       // scan blocks (1024 elems each)

typedef short  short8 __attribute__((ext_vector_type(8)));
typedef float  f32x4  __attribute__((ext_vector_type(4)));

__device__ inline unsigned short f2bf(float f) {
    union { float f; unsigned u; } v; v.f = f;
    unsigned u = v.u;
    return (unsigned short)((u + 0x7FFFu + ((u >> 16) & 1u)) >> 16);   // RNE
}
__device__ inline float bf2f(unsigned short h) {
    union { unsigned u; float f; } v; v.u = ((unsigned)h) << 16;
    return v.f;
}

// ================= CSR build (by dst) =================
__global__ void k_hist(const int4* __restrict__ dst4, int* __restrict__ cnt) {
    int t = blockIdx.x * 256 + threadIdx.x;        // NE/4
    if (t >= NE / 4) return;
    int4 d = dst4[t];
    atomicAdd(&cnt[d.x], 1); atomicAdd(&cnt[d.y], 1);
    atomicAdd(&cnt[d.z], 1); atomicAdd(&cnt[d.w], 1);
}

// --- hierarchical exclusive scan of cnt[SCAN_N] -> off[NN+1], + dinv ---
__global__ __launch_bounds__(256) void k_scanA(const int4* __restrict__ cnt4,
                                               int* __restrict__ bsum) {
    __shared__ int lds[256];
    const int b = blockIdx.x, t = threadIdx.x;
    int4 c = cnt4[b * 256 + t];
    lds[t] = c.x + c.y + c.z + c.w;
    __syncthreads();
    for (int d = 128; d > 0; d >>= 1) {
        if (t < d) lds[t] += lds[t + d];
        __syncthreads();
    }
    if (t == 0) bsum[b] = lds[0];
}
__global__ void k_scanB(const int* __restrict__ bsum, int* __restrict__ boff) {
    int t = threadIdx.x;                       // 64
    int v = (t < SCAN_B) ? bsum[t] : 0;
    int orig = v;
    for (int d = 1; d < 64; d <<= 1) {
        int u = __shfl_up(v, d);
        if (t >= d) v += u;
    }
    if (t < SCAN_B) boff[t] = v - orig;        // exclusive
}
__global__ __launch_bounds__(256) void k_scanC(const int4* __restrict__ cnt4,
                                               const int* __restrict__ boff,
                                               int* __restrict__ off,
                                               float* __restrict__ dinv) {
    __shared__ int lds[256];
    const int b = blockIdx.x, t = threadIdx.x;
    int4 c = cnt4[b * 256 + t];
    int s = c.x + c.y + c.z + c.w;
    lds[t] = s;
    __syncthreads();
    for (int d = 1; d < 256; d <<= 1) {
        int add = (t >= d) ? lds[t - d] : 0;
        __syncthreads();
        lds[t] += add;
        __syncthreads();
    }
    int run = boff[b] + lds[t] - s;            // exclusive prefix at first elem
    int base = b * 1024 + t * 4;
    if (base < NN) { off[base] = run; dinv[base] = rsqrtf((float)c.x + 1.0f); }
    run += c.x;
    if (base + 1 < NN) { off[base + 1] = run; dinv[base + 1] = rsqrtf((float)c.y + 1.0f); }
    run += c.y;
    if (base + 2 < NN) { off[base + 2] = run; dinv[base + 2] = rsqrtf((float)c.z + 1.0f); }
    run += c.z;
    if (base + 3 < NN) { off[base + 3] = run; dinv[base + 3] = rsqrtf((float)c.w + 1.0f); }
    if (b == 0 && t == 0) off[NN] = NE;
}

// bucket: consumes cnt (atomicSub), writes csr src lists
__global__ void k_bucket(const int4* __restrict__ src4, const int4* __restrict__ dst4,
                         const int* __restrict__ off, int* __restrict__ cnt,
                         int* __restrict__ csr) {
    int t = blockIdx.x * 256 + threadIdx.x;        // NE/4
    if (t >= NE / 4) return;
    int4 s = src4[t];
    int4 d = dst4[t];
    csr[off[d.x] + atomicSub(&cnt[d.x], 1) - 1] = s.x;
    csr[off[d.y] + atomicSub(&cnt[d.y], 1) - 1] = s.y;
    csr[off[d.z] + atomicSub(&cnt[d.z], 1) - 1] = s.z;
    csr[off[d.w] + atomicSub(&cnt[d.w], 1) - 1] = s.w;
}

// ================= fused prep: xs = bf16(dinv*x), W1t, W2t =================
// grid = 6250 (xs) + 256 (w1t) + 512 (w2t) blocks of 256
__global__ __launch_bounds__(256) void k_prep(
        const float4* __restrict__ x4, const float* __restrict__ dinv,
        ushort4* __restrict__ xs,
        const float* __restrict__ W1, unsigned short* __restrict__ w1t,
        const float* __restrict__ W2, unsigned short* __restrict__ w2t) {
    int b = blockIdx.x;
    if (b < 6250) {                                // NN*32 = 1,600,000 = 6250*256
        int t = b * 256 + threadIdx.x;
        float dn = dinv[t >> 5];
        float4 v = x4[t];
        ushort4 o;
        o.x = f2bf(dn * v.x); o.y = f2bf(dn * v.y);
        o.z = f2bf(dn * v.z); o.w = f2bf(dn * v.w);
        xs[t] = o;
    } else if (b < 6250 + 256) {                   // W1 [128,512] -> [512,128]
        int t = (b - 6250) * 256 + threadIdx.x;
        int n = t >> 7, k = t & 127;
        w1t[t] = f2bf(W1[k * F1 + n]);
    } else {                                       // W2 [512,250] -> [256,512], pad
        int t = (b - 6506) * 256 + threadIdx.x;
        int n = t >> 9, k = t & 511;
        w2t[t] = (n < F2) ? f2bf(W2[k * F2 + n]) : (unsigned short)0;
    }
}

// ================= gathers (CSR, pre-scaled rows, 4x unrolled) =================
// agg1[n] = bf16( dinv[n] * ( xs[n] + sum_{s} xs[s] ) )   128-dim
__global__ __launch_bounds__(256) void k_gather1(
        const ushort4* __restrict__ xs, const int* __restrict__ off,
        const int* __restrict__ csr, const float* __restrict__ dinv,
        ushort4* __restrict__ agg) {
    int n = blockIdx.x * 8 + (threadIdx.x >> 5);
    int c = threadIdx.x & 31;
    if (n >= NN) return;
    float dn = dinv[n];
    ushort4 a = xs[(size_t)n * 32 + c];
    float sx = bf2f(a.x), sy = bf2f(a.y), sz = bf2f(a.z), sw = bf2f(a.w);
    int j = off[n], e1 = off[n + 1];
    for (; j + 4 <= e1; j += 4) {
        int s0 = csr[j], s1 = csr[j + 1], s2 = csr[j + 2], s3 = csr[j + 3];
        ushort4 v0 = xs[(size_t)s0 * 32 + c];
        ushort4 v1 = xs[(size_t)s1 * 32 + c];
        ushort4 v2 = xs[(size_t)s2 * 32 + c];
        ushort4 v3 = xs[(size_t)s3 * 32 + c];
        sx += bf2f(v0.x) + bf2f(v1.x) + bf2f(v2.x) + bf2f(v3.x);
        sy += bf2f(v0.y) + bf2f(v1.y) + bf2f(v2.y) + bf2f(v3.y);
        sz += bf2f(v0.z) + bf2f(v1.z) + bf2f(v2.z) + bf2f(v3.z);
        sw += bf2f(v0.w) + bf2f(v1.w) + bf2f(v2.w) + bf2f(v3.w);
    }
    for (; j < e1; ++j) {
        int s = csr[j];
        ushort4 v = xs[(size_t)s * 32 + c];
        sx += bf2f(v.x); sy += bf2f(v.y); sz += bf2f(v.z); sw += bf2f(v.w);
    }
    ushort4 o;
    o.x = f2bf(dn * sx); o.y = f2bf(dn * sy); o.z = f2bf(dn * sz); o.w = f2bf(dn * sw);
    agg[(size_t)n * 32 + c] = o;
}

// out[n] = relu( dinv[n]*( t2s[n] + sum t2s[s] ) + b2 )  (t2s pre-scaled by dinv[row])
__global__ __launch_bounds__(256) void k_gather2(
        const ushort4* __restrict__ t4, const int* __restrict__ off,
        const int* __restrict__ csr, const float* __restrict__ dinv,
        const float* __restrict__ b2, float* __restrict__ out) {
    int n = blockIdx.x * 4 + (threadIdx.x >> 6);
    int c = threadIdx.x & 63;                     // 4 bf16 per lane over 256 cols
    if (n >= NN) return;
    float dn = dinv[n];
    ushort4 a = t4[(size_t)n * 64 + c];
    float sx = bf2f(a.x), sy = bf2f(a.y), sz = bf2f(a.z), sw = bf2f(a.w);
    int j = off[n], e1 = off[n + 1];
    for (; j + 4 <= e1; j += 4) {
        int s0 = csr[j], s1 = csr[j + 1], s2 = csr[j + 2], s3 = csr[j + 3];
        ushort4 v0 = t4[(size_t)s0 * 64 + c];
        ushort4 v1 = t4[(size_t)s1 * 64 + c];
        ushort4 v2 = t4[(size_t)s2 * 64 + c];
        ushort4 v3 = t4[(size_t)s3 * 64 + c];
        sx += bf2f(v0.x) + bf2f(v1.x) + bf2f(v2.x) + bf2f(v3.x);
        sy += bf2f(v0.y) + bf2f(v1.y) + bf2f(v2.y) + bf2f(v3.y);
        sz += bf2f(v0.z) + bf2f(v1.z) + bf2f(v2.z) + bf2f(v3.z);
        sw += bf2f(v0.w) + bf2f(v1.w) + bf2f(v2.w) + bf2f(v3.w);
    }
    for (; j < e1; ++j) {
        int s = csr[j];
        ushort4 v = t4[(size_t)s * 64 + c];
        sx += bf2f(v.x); sy += bf2f(v.y); sz += bf2f(v.z); sw += bf2f(v.w);
    }
    int f = c * 4;
    float* o = out + (size_t)n * F2;
    if (f     < F2) o[f]     = fmaxf(dn * sx + b2[f],     0.f);
    if (f + 1 < F2) o[f + 1] = fmaxf(dn * sy + b2[f + 1], 0.f);
    if (f + 2 < F2) o[f + 2] = fmaxf(dn * sz + b2[f + 2], 0.f);
    if (f + 3 < F2) o[f + 3] = fmaxf(dn * sw + b2[f + 3], 0.f);
}

// ================= bf16 MFMA GEMM: C = A[M,K] * Bt[N,K]^T (+bias,relu,rowscale) ======
// 128x128 tile, BK=32, 4 waves (2x2), each wave 64x64 via 4x4 frags of 16x16x32.
// LDS slot-swizzle: chunk q of row m stored at slot q ^ ((m>>1)&3) -> frag reads 2-way (free).
__global__ __launch_bounds__(256) void k_gemm_bf16(
        const unsigned short* __restrict__ A, int lda,
        const unsigned short* __restrict__ Bt, int ldb,
        unsigned short* __restrict__ C, int ldc,
        const float* __restrict__ bias, int do_relu,
        const float* __restrict__ rowscale,
        int M, int K)
{
    __shared__ unsigned short As[128 * 32];   // 8 KB
    __shared__ unsigned short Bs[128 * 32];   // 8 KB

    const int tid = threadIdx.x;
    const int wv = tid >> 6, ln = tid & 63;
    const int m0 = blockIdx.y * 128, n0 = blockIdx.x * 128;
    const int wy = wv >> 1, wx = wv & 1;
    const int lane15 = ln & 15, quad = ln >> 4;

    const unsigned short* ag[2];
    const unsigned short* bg[2];
    int ldsoff[2];
#pragma unroll
    for (int i = 0; i < 2; ++i) {
        int c = (i * 4 + wv) * 64 + ln;
        int m = c >> 2, q = c & 3;
        int gq = q ^ ((m >> 1) & 3);          // which global 8-elem chunk lands here
        int arow = m0 + m; if (arow > M - 1) arow = M - 1;   // clamp tail tile
        ag[i] = A  + (size_t)arow * lda + gq * 8;
        bg[i] = Bt + (size_t)(n0 + m) * ldb + gq * 8;
        ldsoff[i] = (i * 4 + wv) * 512;       // elements; wave-uniform
    }

    f32x4 acc[4][4];
#pragma unroll
    for (int fy = 0; fy < 4; ++fy)
#pragma unroll
        for (int fx = 0; fx < 4; ++fx)
            acc[fy][fx] = (f32x4)0.0f;

    for (int k0 = 0; k0 < K; k0 += 32) {
#pragma unroll
        for (int i = 0; i < 2; ++i) {
            __builtin_amdgcn_global_load_lds(
                (const __attribute__((address_space(1))) void*)ag[i],
                (__attribute__((address_space(3))) void*)(As + ldsoff[i]), 16, 0, 0);
            __builtin_amdgcn_global_load_lds(
                (const __attribute__((address_space(1))) void*)bg[i],
                (__attribute__((address_space(3))) void*)(Bs + ldsoff[i]), 16, 0, 0);
            ag[i] += 32; bg[i] += 32;
        }
        __syncthreads();

        short8 af[4], bf[4];
#pragma unroll
        for (int f = 0; f < 4; ++f) {
            int mA = wy * 64 + f * 16 + lane15;
            int sA = quad ^ ((mA >> 1) & 3);
            af[f] = *(const short8*)(As + mA * 32 + sA * 8);
            int nB = wx * 64 + f * 16 + lane15;
            int sB = quad ^ ((nB >> 1) & 3);
            bf[f] = *(const short8*)(Bs + nB * 32 + sB * 8);
        }
#pragma unroll
        for (int fy = 0; fy < 4; ++fy)
#pragma unroll
            for (int fx = 0; fx < 4; ++fx)
                acc[fy][fx] = __builtin_amdgcn_mfma_f32_16x16x32_bf16(
                    af[fy], bf[fx], acc[fy][fx], 0, 0, 0);
        __syncthreads();
    }

    // epilogue: C/D layout col=lane&15, row=quad*4+reg (m89-verified)
#pragma unroll
    for (int fy = 0; fy < 4; ++fy) {
        int rowb = m0 + wy * 64 + fy * 16 + quad * 4;
        float rs[4] = {1.f, 1.f, 1.f, 1.f};
        if (rowscale) {
#pragma unroll
            for (int r = 0; r < 4; ++r) {
                int row = rowb + r; if (row > M - 1) row = M - 1;
                rs[r] = rowscale[row];
            }
        }
#pragma unroll
        for (int fx = 0; fx < 4; ++fx) {
            int col = n0 + wx * 64 + fx * 16 + lane15;
            float bia = bias ? bias[col] : 0.0f;
            f32x4 v = acc[fy][fx];
#pragma unroll
            for (int r = 0; r < 4; ++r) {
                int row = rowb + r;
                if (row < M) {
                    float val = v[r] + bia;
                    if (do_relu) val = fmaxf(val, 0.0f);
                    val *= rs[r];
                    C[(size_t)row * ldc + col] = f2bf(val);
                }
            }
        }
    }
}

extern "C" void kernel_launch(void* const* d_in, const int* in_sizes, int n_in,
                              void* d_out, int out_size, void* d_ws, size_t ws_size,
                              hipStream_t stream) {
    const float* x  = (const float*)d_in[0];
    const int*   ei = (const int*)d_in[1];
    const float* W1 = (const float*)d_in[2];
    const float* b1 = (const float*)d_in[3];
    const float* W2 = (const float*)d_in[4];
    const float* b2 = (const float*)d_in[5];
    float* out = (float*)d_out;

    // workspace carve (256 B aligned)
    char* p = (char*)d_ws;
    auto carve = [&](size_t bytes) { char* r = p; p += (bytes + 255) & ~(size_t)255; return r; };
    float*          dinv = (float*)carve(NN * 4);
    int*            cnt  = (int*)carve(SCAN_N * 4);
    int*            off  = (int*)carve((NN + 1) * 4);
    int*            csr  = (int*)carve(NE * 4);
    int*            bsum = (int*)carve(64 * 4);
    int*            boff = (int*)carve(64 * 4);
    unsigned short* xs   = (unsigned short*)carve((size_t)NN * F0 * 2);
    unsigned short* agg1 = (unsigned short*)carve((size_t)NN * F0 * 2);
    unsigned short* h1   = (unsigned short*)carve((size_t)NN * F1 * 2);
    unsigned short* t2s  = (unsigned short*)carve((size_t)NN * 256 * 2);
    unsigned short* w1t  = (unsigned short*)carve((size_t)F1 * F0 * 2);
    unsigned short* w2t  = (unsigned short*)carve((size_t)256 * F1 * 2);

    // CSR + norm
    hipMemsetAsync(cnt, 0, SCAN_N * sizeof(int), stream);
    k_hist <<<(NE / 4 + 255) / 256, 256, 0, stream>>>((const int4*)(ei + NE), cnt);
    k_scanA<<<SCAN_B, 256, 0, stream>>>((const int4*)cnt, bsum);
    k_scanB<<<1, 64, 0, stream>>>(bsum, boff);
    k_scanC<<<SCAN_B, 256, 0, stream>>>((const int4*)cnt, boff, off, dinv);
    k_bucket<<<(NE / 4 + 255) / 256, 256, 0, stream>>>(
        (const int4*)ei, (const int4*)(ei + NE), off, cnt, csr);

    // fused prep: xs = bf16(dinv*x), W1t, W2t
    k_prep<<<6250 + 256 + 512, 256, 0, stream>>>(
        (const float4*)x, dinv, (ushort4*)xs, W1, w1t, W2, w2t);

    // layer 1: aggregate (128-dim) then MFMA GEMM + bias + relu -> h1 bf16
    k_gather1<<<(NN + 7) / 8, 256, 0, stream>>>((const ushort4*)xs, off, csr, dinv,
                                                (ushort4*)agg1);
    k_gemm_bf16<<<dim3(F1 / 128, MT), 256, 0, stream>>>(
        agg1, F0, w1t, F0, h1, F1, b1, 1, nullptr, NN, F0);

    // layer 2: MFMA GEMM (rowscale=dinv) -> t2s bf16, then gather + bias + relu
    k_gemm_bf16<<<dim3(256 / 128, MT), 256, 0, stream>>>(
        h1, F1, w2t, F1, t2s, 256, nullptr, 0, dinv, NN, F1);
    k_gather2<<<(NN + 3) / 4, 256, 0, stream>>>((const ushort4*)t2s, off, csr, dinv,
                                                b2, out);
}

// Round 6
// 268.183 us; speedup vs baseline: 3.7760x; 1.0891x over previous
//
#include <hip/hip_runtime.h>

// Problem constants
constexpr int NN  = 50000;   // nodes
constexpr int NE  = 400000;  // edges
constexpr int F0  = 128;     // input features
constexpr int F1  = 512;     // hidden features
constexpr int F2  = 250;     // output features
constexpr int MT64 = 782;    // M tiles of 64 (782*64 = 50048)
constexpr int SCAN_N = 50176;    // 49 * 1024, padded count array
constexpr int SCAN_B = 49;       // scan blocks (1024 elems each)

typedef short  short8 __attribute__((ext_vector_type(8)));
typedef float  f32x4  __attribute__((ext_vector_type(4)));

__device__ inline unsigned short f2bf(float f) {
    union { float f; unsigned u; } v; v.f = f;
    unsigned u = v.u;
    return (unsigned short)((u + 0x7FFFu + ((u >> 16) & 1u)) >> 16);   // RNE
}
__device__ inline float bf2f(unsigned short h) {
    union { unsigned u; float f; } v; v.u = ((unsigned)h) << 16;
    return v.f;
}

// ================= CSR build (by dst) =================
__global__ void k_hist(const int4* __restrict__ dst4, int* __restrict__ cnt) {
    int t = blockIdx.x * 256 + threadIdx.x;        // NE/4
    if (t >= NE / 4) return;
    int4 d = dst4[t];
    atomicAdd(&cnt[d.x], 1); atomicAdd(&cnt[d.y], 1);
    atomicAdd(&cnt[d.z], 1); atomicAdd(&cnt[d.w], 1);
}

// --- hierarchical exclusive scan of cnt[SCAN_N] -> off[NN+1], + dinv ---
__global__ __launch_bounds__(256) void k_scanA(const int4* __restrict__ cnt4,
                                               int* __restrict__ bsum) {
    __shared__ int lds[256];
    const int b = blockIdx.x, t = threadIdx.x;
    int4 c = cnt4[b * 256 + t];
    lds[t] = c.x + c.y + c.z + c.w;
    __syncthreads();
    for (int d = 128; d > 0; d >>= 1) {
        if (t < d) lds[t] += lds[t + d];
        __syncthreads();
    }
    if (t == 0) bsum[b] = lds[0];
}
__global__ void k_scanB(const int* __restrict__ bsum, int* __restrict__ boff) {
    int t = threadIdx.x;                       // 64
    int v = (t < SCAN_B) ? bsum[t] : 0;
    int orig = v;
    for (int d = 1; d < 64; d <<= 1) {
        int u = __shfl_up(v, d);
        if (t >= d) v += u;
    }
    if (t < SCAN_B) boff[t] = v - orig;        // exclusive
}
__global__ __launch_bounds__(256) void k_scanC(const int4* __restrict__ cnt4,
                                               const int* __restrict__ boff,
                                               int* __restrict__ off,
                                               float* __restrict__ dinv) {
    __shared__ int lds[256];
    const int b = blockIdx.x, t = threadIdx.x;
    int4 c = cnt4[b * 256 + t];
    int s = c.x + c.y + c.z + c.w;
    lds[t] = s;
    __syncthreads();
    for (int d = 1; d < 256; d <<= 1) {
        int add = (t >= d) ? lds[t - d] : 0;
        __syncthreads();
        lds[t] += add;
        __syncthreads();
    }
    int run = boff[b] + lds[t] - s;            // exclusive prefix at first elem
    int base = b * 1024 + t * 4;
    if (base < NN) { off[base] = run; dinv[base] = rsqrtf((float)c.x + 1.0f); }
    run += c.x;
    if (base + 1 < NN) { off[base + 1] = run; dinv[base + 1] = rsqrtf((float)c.y + 1.0f); }
    run += c.y;
    if (base + 2 < NN) { off[base + 2] = run; dinv[base + 2] = rsqrtf((float)c.z + 1.0f); }
    run += c.z;
    if (base + 3 < NN) { off[base + 3] = run; dinv[base + 3] = rsqrtf((float)c.w + 1.0f); }
    if (b == 0 && t == 0) off[NN] = NE;
}

// bucket: consumes cnt (atomicSub), writes csr src lists
__global__ void k_bucket(const int4* __restrict__ src4, const int4* __restrict__ dst4,
                         const int* __restrict__ off, int* __restrict__ cnt,
                         int* __restrict__ csr) {
    int t = blockIdx.x * 256 + threadIdx.x;        // NE/4
    if (t >= NE / 4) return;
    int4 s = src4[t];
    int4 d = dst4[t];
    csr[off[d.x] + atomicSub(&cnt[d.x], 1) - 1] = s.x;
    csr[off[d.y] + atomicSub(&cnt[d.y], 1) - 1] = s.y;
    csr[off[d.z] + atomicSub(&cnt[d.z], 1) - 1] = s.z;
    csr[off[d.w] + atomicSub(&cnt[d.w], 1) - 1] = s.w;
}

// ================= fused prep: xs = bf16(dinv*x), W1t, W2t =================
__global__ __launch_bounds__(256) void k_prep(
        const float4* __restrict__ x4, const float* __restrict__ dinv,
        ushort4* __restrict__ xs,
        const float* __restrict__ W1, unsigned short* __restrict__ w1t,
        const float* __restrict__ W2, unsigned short* __restrict__ w2t) {
    int b = blockIdx.x;
    if (b < 6250) {                                // NN*32 = 1,600,000 = 6250*256
        int t = b * 256 + threadIdx.x;
        float dn = dinv[t >> 5];
        float4 v = x4[t];
        ushort4 o;
        o.x = f2bf(dn * v.x); o.y = f2bf(dn * v.y);
        o.z = f2bf(dn * v.z); o.w = f2bf(dn * v.w);
        xs[t] = o;
    } else if (b < 6250 + 256) {                   // W1 [128,512] -> [512,128]
        int t = (b - 6250) * 256 + threadIdx.x;
        int n = t >> 7, k = t & 127;
        w1t[t] = f2bf(W1[k * F1 + n]);
    } else {                                       // W2 [512,250] -> [256,512], pad
        int t = (b - 6506) * 256 + threadIdx.x;
        int n = t >> 9, k = t & 511;
        w2t[t] = (n < F2) ? f2bf(W2[k * F2 + n]) : (unsigned short)0;
    }
}

// ================= gathers (CSR, pre-scaled rows, 4x unrolled) =================
__global__ __launch_bounds__(256) void k_gather1(
        const ushort4* __restrict__ xs, const int* __restrict__ off,
        const int* __restrict__ csr, const float* __restrict__ dinv,
        ushort4* __restrict__ agg) {
    int n = blockIdx.x * 8 + (threadIdx.x >> 5);
    int c = threadIdx.x & 31;
    if (n >= NN) return;
    float dn = dinv[n];
    ushort4 a = xs[(size_t)n * 32 + c];
    float sx = bf2f(a.x), sy = bf2f(a.y), sz = bf2f(a.z), sw = bf2f(a.w);
    int j = off[n], e1 = off[n + 1];
    for (; j + 4 <= e1; j += 4) {
        int s0 = csr[j], s1 = csr[j + 1], s2 = csr[j + 2], s3 = csr[j + 3];
        ushort4 v0 = xs[(size_t)s0 * 32 + c];
        ushort4 v1 = xs[(size_t)s1 * 32 + c];
        ushort4 v2 = xs[(size_t)s2 * 32 + c];
        ushort4 v3 = xs[(size_t)s3 * 32 + c];
        sx += bf2f(v0.x) + bf2f(v1.x) + bf2f(v2.x) + bf2f(v3.x);
        sy += bf2f(v0.y) + bf2f(v1.y) + bf2f(v2.y) + bf2f(v3.y);
        sz += bf2f(v0.z) + bf2f(v1.z) + bf2f(v2.z) + bf2f(v3.z);
        sw += bf2f(v0.w) + bf2f(v1.w) + bf2f(v2.w) + bf2f(v3.w);
    }
    for (; j < e1; ++j) {
        int s = csr[j];
        ushort4 v = xs[(size_t)s * 32 + c];
        sx += bf2f(v.x); sy += bf2f(v.y); sz += bf2f(v.z); sw += bf2f(v.w);
    }
    ushort4 o;
    o.x = f2bf(dn * sx); o.y = f2bf(dn * sy); o.z = f2bf(dn * sz); o.w = f2bf(dn * sw);
    agg[(size_t)n * 32 + c] = o;
}

__global__ __launch_bounds__(256) void k_gather2(
        const ushort4* __restrict__ t4, const int* __restrict__ off,
        const int* __restrict__ csr, const float* __restrict__ dinv,
        const float* __restrict__ b2, float* __restrict__ out) {
    int n = blockIdx.x * 4 + (threadIdx.x >> 6);
    int c = threadIdx.x & 63;                     // 4 bf16 per lane over 256 cols
    if (n >= NN) return;
    float dn = dinv[n];
    ushort4 a = t4[(size_t)n * 64 + c];
    float sx = bf2f(a.x), sy = bf2f(a.y), sz = bf2f(a.z), sw = bf2f(a.w);
    int j = off[n], e1 = off[n + 1];
    for (; j + 4 <= e1; j += 4) {
        int s0 = csr[j], s1 = csr[j + 1], s2 = csr[j + 2], s3 = csr[j + 3];
        ushort4 v0 = t4[(size_t)s0 * 64 + c];
        ushort4 v1 = t4[(size_t)s1 * 64 + c];
        ushort4 v2 = t4[(size_t)s2 * 64 + c];
        ushort4 v3 = t4[(size_t)s3 * 64 + c];
        sx += bf2f(v0.x) + bf2f(v1.x) + bf2f(v2.x) + bf2f(v3.x);
        sy += bf2f(v0.y) + bf2f(v1.y) + bf2f(v2.y) + bf2f(v3.y);
        sz += bf2f(v0.z) + bf2f(v1.z) + bf2f(v2.z) + bf2f(v3.z);
        sw += bf2f(v0.w) + bf2f(v1.w) + bf2f(v2.w) + bf2f(v3.w);
    }
    for (; j < e1; ++j) {
        int s = csr[j];
        ushort4 v = t4[(size_t)s * 64 + c];
        sx += bf2f(v.x); sy += bf2f(v.y); sz += bf2f(v.z); sw += bf2f(v.w);
    }
    int f = c * 4;
    float* o = out + (size_t)n * F2;
    if (f     < F2) o[f]     = fmaxf(dn * sx + b2[f],     0.f);
    if (f + 1 < F2) o[f + 1] = fmaxf(dn * sy + b2[f + 1], 0.f);
    if (f + 2 < F2) o[f + 2] = fmaxf(dn * sz + b2[f + 2], 0.f);
    if (f + 3 < F2) o[f + 3] = fmaxf(dn * sw + b2[f + 3], 0.f);
}

// ========== bf16 MFMA GEMM: C = A[M,K] * Bt[N,K]^T (+bias,relu,rowscale) ==========
// 64x128 tile, BK=32, double-buffered LDS, one barrier per K-step with
// post-barrier prefetch (prefetch overlaps the MFMA phase; the barrier's
// vmcnt(0) drain then waits on a load that has had a full compute phase).
// 4 waves (2x2): each wave 32 rows x 64 cols = 2x4 frags of 16x16x32.
// LDS slot-swizzle: chunk q of row m stored at slot q ^ ((m>>1)&3) -> frag
// reads are <=2-way (free, m136).
__global__ __launch_bounds__(256) void k_gemm_bf16(
        const unsigned short* __restrict__ A, int lda,
        const unsigned short* __restrict__ Bt, int ldb,
        unsigned short* __restrict__ C, int ldc,
        const float* __restrict__ bias, int do_relu,
        const float* __restrict__ rowscale,
        int M, int K)
{
    __shared__ unsigned short As[2][64 * 32];    // 2 x 4 KB
    __shared__ unsigned short Bs[2][128 * 32];   // 2 x 8 KB

    const int tid = threadIdx.x;
    const int wv = tid >> 6, ln = tid & 63;
    const int m0 = blockIdx.y * 64, n0 = blockIdx.x * 128;
    const int wy = wv >> 1, wx = wv & 1;
    const int lane15 = ln & 15, quad = ln >> 4;

    // A staging: one 16B chunk per thread (64 rows x 4 slots = 256 chunks)
    {
    }
    const int cA = tid, mA_ = cA >> 2, qA = cA & 3;
    const int gqA = qA ^ ((mA_ >> 1) & 3);
    int arow = m0 + mA_; if (arow > M - 1) arow = M - 1;   // clamp tail tile
    const unsigned short* agp = A + (size_t)arow * lda + gqA * 8;
    const int aofs = wv * 512;                  // wave-uniform LDS elem offset

    // B staging: two chunks per thread (128 rows x 4 slots = 512 chunks)
    const unsigned short* bgp[2];
    int bofs[2];
#pragma unroll
    for (int i = 0; i < 2; ++i) {
        int c = (i * 4 + wv) * 64 + ln;
        int m = c >> 2, q = c & 3;
        int gq = q ^ ((m >> 1) & 3);
        bgp[i] = Bt + (size_t)(n0 + m) * ldb + gq * 8;
        bofs[i] = (i * 4 + wv) * 512;
    }

    f32x4 acc[2][4];
#pragma unroll
    for (int fy = 0; fy < 2; ++fy)
#pragma unroll
        for (int fx = 0; fx < 4; ++fx)
            acc[fy][fx] = (f32x4)0.0f;

    const int NK = K >> 5;

    // prologue: stage step 0 into buffer 0
    __builtin_amdgcn_global_load_lds(
        (const __attribute__((address_space(1))) void*)agp,
        (__attribute__((address_space(3))) void*)(&As[0][0] + aofs), 16, 0, 0);
#pragma unroll
    for (int i = 0; i < 2; ++i)
        __builtin_amdgcn_global_load_lds(
            (const __attribute__((address_space(1))) void*)bgp[i],
            (__attribute__((address_space(3))) void*)(&Bs[0][0] + bofs[i]), 16, 0, 0);

    for (int ks = 0; ks < NK; ++ks) {
        __syncthreads();                         // buf[ks&1] ready (vmcnt drain)
        if (ks + 1 < NK) {                       // prefetch next into other buf
            int ko = (ks + 1) << 5;
            int nb = (ks + 1) & 1;
            __builtin_amdgcn_global_load_lds(
                (const __attribute__((address_space(1))) void*)(agp + ko),
                (__attribute__((address_space(3))) void*)(&As[nb][0] + aofs), 16, 0, 0);
#pragma unroll
            for (int i = 0; i < 2; ++i)
                __builtin_amdgcn_global_load_lds(
                    (const __attribute__((address_space(1))) void*)(bgp[i] + ko),
                    (__attribute__((address_space(3))) void*)(&Bs[nb][0] + bofs[i]), 16, 0, 0);
        }
        const int b = ks & 1;
        short8 af[2], bf[4];
#pragma unroll
        for (int f = 0; f < 2; ++f) {
            int mA = wy * 32 + f * 16 + lane15;
            int sA = quad ^ ((mA >> 1) & 3);
            af[f] = *(const short8*)(&As[b][0] + mA * 32 + sA * 8);
        }
#pragma unroll
        for (int f = 0; f < 4; ++f) {
            int nB = wx * 64 + f * 16 + lane15;
            int sB = quad ^ ((nB >> 1) & 3);
            bf[f] = *(const short8*)(&Bs[b][0] + nB * 32 + sB * 8);
        }
#pragma unroll
        for (int fy = 0; fy < 2; ++fy)
#pragma unroll
            for (int fx = 0; fx < 4; ++fx)
                acc[fy][fx] = __builtin_amdgcn_mfma_f32_16x16x32_bf16(
                    af[fy], bf[fx], acc[fy][fx], 0, 0, 0);
    }

    // epilogue: C/D layout col=lane&15, row=quad*4+reg (m89-verified)
#pragma unroll
    for (int fy = 0; fy < 2; ++fy) {
        int rowb = m0 + wy * 32 + fy * 16 + quad * 4;
        float rs[4] = {1.f, 1.f, 1.f, 1.f};
        if (rowscale) {
#pragma unroll
            for (int r = 0; r < 4; ++r) {
                int row = rowb + r; if (row > M - 1) row = M - 1;
                rs[r] = rowscale[row];
            }
        }
#pragma unroll
        for (int fx = 0; fx < 4; ++fx) {
            int col = n0 + wx * 64 + fx * 16 + lane15;
            float bia = bias ? bias[col] : 0.0f;
            f32x4 v = acc[fy][fx];
#pragma unroll
            for (int r = 0; r < 4; ++r) {
                int row = rowb + r;
                if (row < M) {
                    float val = v[r] + bia;
                    if (do_relu) val = fmaxf(val, 0.0f);
                    val *= rs[r];
                    C[(size_t)row * ldc + col] = f2bf(val);
                }
            }
        }
    }
}

extern "C" void kernel_launch(void* const* d_in, const int* in_sizes, int n_in,
                              void* d_out, int out_size, void* d_ws, size_t ws_size,
                              hipStream_t stream) {
    const float* x  = (const float*)d_in[0];
    const int*   ei = (const int*)d_in[1];
    const float* W1 = (const float*)d_in[2];
    const float* b1 = (const float*)d_in[3];
    const float* W2 = (const float*)d_in[4];
    const float* b2 = (const float*)d_in[5];
    float* out = (float*)d_out;

    // workspace carve (256 B aligned)
    char* p = (char*)d_ws;
    auto carve = [&](size_t bytes) { char* r = p; p += (bytes + 255) & ~(size_t)255; return r; };
    float*          dinv = (float*)carve(NN * 4);
    int*            cnt  = (int*)carve(SCAN_N * 4);
    int*            off  = (int*)carve((NN + 1) * 4);
    int*            csr  = (int*)carve(NE * 4);
    int*            bsum = (int*)carve(64 * 4);
    int*            boff = (int*)carve(64 * 4);
    unsigned short* xs   = (unsigned short*)carve((size_t)NN * F0 * 2);
    unsigned short* agg1 = (unsigned short*)carve((size_t)NN * F0 * 2);
    unsigned short* h1   = (unsigned short*)carve((size_t)NN * F1 * 2);
    unsigned short* t2s  = (unsigned short*)carve((size_t)NN * 256 * 2);
    unsigned short* w1t  = (unsigned short*)carve((size_t)F1 * F0 * 2);
    unsigned short* w2t  = (unsigned short*)carve((size_t)256 * F1 * 2);

    // CSR + norm
    hipMemsetAsync(cnt, 0, SCAN_N * sizeof(int), stream);
    k_hist <<<(NE / 4 + 255) / 256, 256, 0, stream>>>((const int4*)(ei + NE), cnt);
    k_scanA<<<SCAN_B, 256, 0, stream>>>((const int4*)cnt, bsum);
    k_scanB<<<1, 64, 0, stream>>>(bsum, boff);
    k_scanC<<<SCAN_B, 256, 0, stream>>>((const int4*)cnt, boff, off, dinv);
    k_bucket<<<(NE / 4 + 255) / 256, 256, 0, stream>>>(
        (const int4*)ei, (const int4*)(ei + NE), off, cnt, csr);

    // fused prep: xs = bf16(dinv*x), W1t, W2t
    k_prep<<<6250 + 256 + 512, 256, 0, stream>>>(
        (const float4*)x, dinv, (ushort4*)xs, W1, w1t, W2, w2t);

    // layer 1: aggregate (128-dim) then MFMA GEMM + bias + relu -> h1 bf16
    k_gather1<<<(NN + 7) / 8, 256, 0, stream>>>((const ushort4*)xs, off, csr, dinv,
                                                (ushort4*)agg1);
    k_gemm_bf16<<<dim3(F1 / 128, MT64), 256, 0, stream>>>(
        agg1, F0, w1t, F0, h1, F1, b1, 1, nullptr, NN, F0);

    // layer 2: MFMA GEMM (rowscale=dinv) -> t2s bf16, then gather + bias + relu
    k_gemm_bf16<<<dim3(256 / 128, MT64), 256, 0, stream>>>(
        h1, F1, w2t, F1, t2s, 256, nullptr, 0, dinv, NN, F1);
    k_gather2<<<(NN + 3) / 4, 256, 0, stream>>>((const ushort4*)t2s, off, csr, dinv,
                                                b2, out);
}

// Round 7
// 267.350 us; speedup vs baseline: 3.7878x; 1.0031x over previous
//
#include <hip/hip_runtime.h>

// Problem constants
constexpr int NN  = 50000;   // nodes
constexpr int NE  = 400000;  // edges
constexpr int F0  = 128;     // input features
constexpr int F1  = 512;     // hidden features
constexpr int F2  = 250;     // output features
constexpr int MT64 = 782;    // M tiles of 64 (782*64 = 50048)
constexpr int SCAN_N = 50176;    // 49 * 1024, padded count array
constexpr int SCAN_B = 49;       // scan blocks (1024 elems each)

typedef short  short8 __attribute__((ext_vector_type(8)));
typedef float  f32x4  __attribute__((ext_vector_type(4)));

__device__ inline unsigned short f2bf(float f) {
    union { float f; unsigned u; } v; v.f = f;
    unsigned u = v.u;
    return (unsigned short)((u + 0x7FFFu + ((u >> 16) & 1u)) >> 16);   // RNE
}
__device__ inline float bf2f(unsigned short h) {
    union { unsigned u; float f; } v; v.u = ((unsigned)h) << 16;
    return v.f;
}
__device__ inline float bflo(unsigned u) {
    union { unsigned u; float f; } v; v.u = u << 16; return v.f;
}
__device__ inline float bfhi(unsigned u) {
    union { unsigned u; float f; } v; v.u = u & 0xFFFF0000u; return v.f;
}

// ================= CSR build (by dst) =================
__global__ void k_hist(const int4* __restrict__ dst4, int* __restrict__ cnt) {
    int t = blockIdx.x * 256 + threadIdx.x;        // NE/4
    if (t >= NE / 4) return;
    int4 d = dst4[t];
    atomicAdd(&cnt[d.x], 1); atomicAdd(&cnt[d.y], 1);
    atomicAdd(&cnt[d.z], 1); atomicAdd(&cnt[d.w], 1);
}

// --- hierarchical exclusive scan of cnt[SCAN_N] -> off[NN+1], + dinv ---
__global__ __launch_bounds__(256) void k_scanA(const int4* __restrict__ cnt4,
                                               int* __restrict__ bsum) {
    __shared__ int lds[256];
    const int b = blockIdx.x, t = threadIdx.x;
    int4 c = cnt4[b * 256 + t];
    lds[t] = c.x + c.y + c.z + c.w;
    __syncthreads();
    for (int d = 128; d > 0; d >>= 1) {
        if (t < d) lds[t] += lds[t + d];
        __syncthreads();
    }
    if (t == 0) bsum[b] = lds[0];
}
__global__ void k_scanB(const int* __restrict__ bsum, int* __restrict__ boff) {
    int t = threadIdx.x;                       // 64
    int v = (t < SCAN_B) ? bsum[t] : 0;
    int orig = v;
    for (int d = 1; d < 64; d <<= 1) {
        int u = __shfl_up(v, d);
        if (t >= d) v += u;
    }
    if (t < SCAN_B) boff[t] = v - orig;        // exclusive
}
__global__ __launch_bounds__(256) void k_scanC(const int4* __restrict__ cnt4,
                                               const int* __restrict__ boff,
                                               int* __restrict__ off,
                                               float* __restrict__ dinv) {
    __shared__ int lds[256];
    const int b = blockIdx.x, t = threadIdx.x;
    int4 c = cnt4[b * 256 + t];
    int s = c.x + c.y + c.z + c.w;
    lds[t] = s;
    __syncthreads();
    for (int d = 1; d < 256; d <<= 1) {
        int add = (t >= d) ? lds[t - d] : 0;
        __syncthreads();
        lds[t] += add;
        __syncthreads();
    }
    int run = boff[b] + lds[t] - s;            // exclusive prefix at first elem
    int base = b * 1024 + t * 4;
    if (base < NN) { off[base] = run; dinv[base] = rsqrtf((float)c.x + 1.0f); }
    run += c.x;
    if (base + 1 < NN) { off[base + 1] = run; dinv[base + 1] = rsqrtf((float)c.y + 1.0f); }
    run += c.y;
    if (base + 2 < NN) { off[base + 2] = run; dinv[base + 2] = rsqrtf((float)c.z + 1.0f); }
    run += c.z;
    if (base + 3 < NN) { off[base + 3] = run; dinv[base + 3] = rsqrtf((float)c.w + 1.0f); }
    if (b == 0 && t == 0) off[NN] = NE;
}

// bucket: consumes cnt (atomicSub), writes csr src lists
__global__ void k_bucket(const int4* __restrict__ src4, const int4* __restrict__ dst4,
                         const int* __restrict__ off, int* __restrict__ cnt,
                         int* __restrict__ csr) {
    int t = blockIdx.x * 256 + threadIdx.x;        // NE/4
    if (t >= NE / 4) return;
    int4 s = src4[t];
    int4 d = dst4[t];
    csr[off[d.x] + atomicSub(&cnt[d.x], 1) - 1] = s.x;
    csr[off[d.y] + atomicSub(&cnt[d.y], 1) - 1] = s.y;
    csr[off[d.z] + atomicSub(&cnt[d.z], 1) - 1] = s.z;
    csr[off[d.w] + atomicSub(&cnt[d.w], 1) - 1] = s.w;
}

// ================= fused prep: xs = bf16(dinv*x), W1t, W2t =================
__global__ __launch_bounds__(256) void k_prep(
        const float4* __restrict__ x4, const float* __restrict__ dinv,
        ushort4* __restrict__ xs,
        const float* __restrict__ W1, unsigned short* __restrict__ w1t,
        const float* __restrict__ W2, unsigned short* __restrict__ w2t) {
    int b = blockIdx.x;
    if (b < 6250) {                                // NN*32 = 1,600,000 = 6250*256
        int t = b * 256 + threadIdx.x;
        float dn = dinv[t >> 5];
        float4 v = x4[t];
        ushort4 o;
        o.x = f2bf(dn * v.x); o.y = f2bf(dn * v.y);
        o.z = f2bf(dn * v.z); o.w = f2bf(dn * v.w);
        xs[t] = o;
    } else if (b < 6250 + 256) {                   // W1 [128,512] -> [512,128]
        int t = (b - 6250) * 256 + threadIdx.x;
        int n = t >> 7, k = t & 127;
        w1t[t] = f2bf(W1[k * F1 + n]);
    } else {                                       // W2 [512,250] -> [256,512], pad
        int t = (b - 6506) * 256 + threadIdx.x;
        int n = t >> 9, k = t & 511;
        w2t[t] = (n < F2) ? f2bf(W2[k * F2 + n]) : (unsigned short)0;
    }
}

// ================= gathers (CSR, pre-scaled rows, wave-per-node, 8x MLP) ==========
// agg1[n] = bf16( dinv[n] * ( xs[n] + sum_{s} xs[s] ) )   128-dim
// One node per 64-lane wave: csr/off reads are wave-uniform (scalarized);
// lane c covers 2 bf16 cols as one uint.
__global__ __launch_bounds__(256) void k_gather1(
        const unsigned int* __restrict__ xs, const int* __restrict__ off,
        const int* __restrict__ csr, const float* __restrict__ dinv,
        unsigned int* __restrict__ agg) {
    int n = blockIdx.x * 4 + (threadIdx.x >> 6);   // 4 waves / block, 1 node / wave
    int c = threadIdx.x & 63;                      // uint column (2 bf16)
    if (n >= NN) return;
    float dn = dinv[n];
    unsigned a = xs[(size_t)n * 64 + c];
    float s0 = bflo(a), s1 = bfhi(a);
    int j = off[n], e1 = off[n + 1];
    for (; j + 8 <= e1; j += 8) {
        int i0 = csr[j],     i1 = csr[j + 1], i2 = csr[j + 2], i3 = csr[j + 3];
        int i4 = csr[j + 4], i5 = csr[j + 5], i6 = csr[j + 6], i7 = csr[j + 7];
        unsigned v0 = xs[(size_t)i0 * 64 + c];
        unsigned v1 = xs[(size_t)i1 * 64 + c];
        unsigned v2 = xs[(size_t)i2 * 64 + c];
        unsigned v3 = xs[(size_t)i3 * 64 + c];
        unsigned v4 = xs[(size_t)i4 * 64 + c];
        unsigned v5 = xs[(size_t)i5 * 64 + c];
        unsigned v6 = xs[(size_t)i6 * 64 + c];
        unsigned v7 = xs[(size_t)i7 * 64 + c];
        s0 += bflo(v0) + bflo(v1) + bflo(v2) + bflo(v3)
            + bflo(v4) + bflo(v5) + bflo(v6) + bflo(v7);
        s1 += bfhi(v0) + bfhi(v1) + bfhi(v2) + bfhi(v3)
            + bfhi(v4) + bfhi(v5) + bfhi(v6) + bfhi(v7);
    }
    for (; j + 4 <= e1; j += 4) {
        int i0 = csr[j], i1 = csr[j + 1], i2 = csr[j + 2], i3 = csr[j + 3];
        unsigned v0 = xs[(size_t)i0 * 64 + c];
        unsigned v1 = xs[(size_t)i1 * 64 + c];
        unsigned v2 = xs[(size_t)i2 * 64 + c];
        unsigned v3 = xs[(size_t)i3 * 64 + c];
        s0 += bflo(v0) + bflo(v1) + bflo(v2) + bflo(v3);
        s1 += bfhi(v0) + bfhi(v1) + bfhi(v2) + bfhi(v3);
    }
    for (; j < e1; ++j) {
        unsigned v = xs[(size_t)csr[j] * 64 + c];
        s0 += bflo(v); s1 += bfhi(v);
    }
    agg[(size_t)n * 64 + c] =
        (unsigned)f2bf(dn * s0) | ((unsigned)f2bf(dn * s1) << 16);
}

// out[n] = relu( dinv[n]*( t2s[n] + sum t2s[s] ) + b2 )  (t2s pre-scaled by dinv[row])
__global__ __launch_bounds__(256) void k_gather2(
        const ushort4* __restrict__ t4, const int* __restrict__ off,
        const int* __restrict__ csr, const float* __restrict__ dinv,
        const float* __restrict__ b2, float* __restrict__ out) {
    int n = blockIdx.x * 4 + (threadIdx.x >> 6);   // 1 node / wave
    int c = threadIdx.x & 63;                      // 4 bf16 per lane over 256 cols
    if (n >= NN) return;
    float dn = dinv[n];
    ushort4 a = t4[(size_t)n * 64 + c];
    float sx = bf2f(a.x), sy = bf2f(a.y), sz = bf2f(a.z), sw = bf2f(a.w);
    int j = off[n], e1 = off[n + 1];
    for (; j + 8 <= e1; j += 8) {
        int i0 = csr[j],     i1 = csr[j + 1], i2 = csr[j + 2], i3 = csr[j + 3];
        int i4 = csr[j + 4], i5 = csr[j + 5], i6 = csr[j + 6], i7 = csr[j + 7];
        ushort4 v0 = t4[(size_t)i0 * 64 + c];
        ushort4 v1 = t4[(size_t)i1 * 64 + c];
        ushort4 v2 = t4[(size_t)i2 * 64 + c];
        ushort4 v3 = t4[(size_t)i3 * 64 + c];
        ushort4 v4 = t4[(size_t)i4 * 64 + c];
        ushort4 v5 = t4[(size_t)i5 * 64 + c];
        ushort4 v6 = t4[(size_t)i6 * 64 + c];
        ushort4 v7 = t4[(size_t)i7 * 64 + c];
        sx += bf2f(v0.x) + bf2f(v1.x) + bf2f(v2.x) + bf2f(v3.x)
            + bf2f(v4.x) + bf2f(v5.x) + bf2f(v6.x) + bf2f(v7.x);
        sy += bf2f(v0.y) + bf2f(v1.y) + bf2f(v2.y) + bf2f(v3.y)
            + bf2f(v4.y) + bf2f(v5.y) + bf2f(v6.y) + bf2f(v7.y);
        sz += bf2f(v0.z) + bf2f(v1.z) + bf2f(v2.z) + bf2f(v3.z)
            + bf2f(v4.z) + bf2f(v5.z) + bf2f(v6.z) + bf2f(v7.z);
        sw += bf2f(v0.w) + bf2f(v1.w) + bf2f(v2.w) + bf2f(v3.w)
            + bf2f(v4.w) + bf2f(v5.w) + bf2f(v6.w) + bf2f(v7.w);
    }
    for (; j + 4 <= e1; j += 4) {
        int i0 = csr[j], i1 = csr[j + 1], i2 = csr[j + 2], i3 = csr[j + 3];
        ushort4 v0 = t4[(size_t)i0 * 64 + c];
        ushort4 v1 = t4[(size_t)i1 * 64 + c];
        ushort4 v2 = t4[(size_t)i2 * 64 + c];
        ushort4 v3 = t4[(size_t)i3 * 64 + c];
        sx += bf2f(v0.x) + bf2f(v1.x) + bf2f(v2.x) + bf2f(v3.x);
        sy += bf2f(v0.y) + bf2f(v1.y) + bf2f(v2.y) + bf2f(v3.y);
        sz += bf2f(v0.z) + bf2f(v1.z) + bf2f(v2.z) + bf2f(v3.z);
        sw += bf2f(v0.w) + bf2f(v1.w) + bf2f(v2.w) + bf2f(v3.w);
    }
    for (; j < e1; ++j) {
        ushort4 v = t4[(size_t)csr[j] * 64 + c];
        sx += bf2f(v.x); sy += bf2f(v.y); sz += bf2f(v.z); sw += bf2f(v.w);
    }
    int f = c * 4;
    float* o = out + (size_t)n * F2;
    if (f     < F2) o[f]     = fmaxf(dn * sx + b2[f],     0.f);
    if (f + 1 < F2) o[f + 1] = fmaxf(dn * sy + b2[f + 1], 0.f);
    if (f + 2 < F2) o[f + 2] = fmaxf(dn * sz + b2[f + 2], 0.f);
    if (f + 3 < F2) o[f + 3] = fmaxf(dn * sw + b2[f + 3], 0.f);
}

// ========== gemm1: single-shot K=128 bf16 MFMA GEMM (+bias+relu) ==========
// C[M,512] = A[M,128] * Bt[512,128]^T. 64x128 tile, whole K in LDS, ONE barrier.
// 16-slot swizzle: chunk q of row m holds global chunk q^(m&15) -> frag
// ds_read_b128 2-way (free), staging linear (DMA constraint).
__global__ __launch_bounds__(256) void k_gemm1(
        const unsigned short* __restrict__ A,
        const unsigned short* __restrict__ Bt,
        unsigned short* __restrict__ C,
        const float* __restrict__ bias, int M)
{
    __shared__ unsigned short As[64 * 128];    // 16 KB
    __shared__ unsigned short Bs[128 * 128];   // 32 KB

    const int tid = threadIdx.x;
    const int wv = tid >> 6, ln = tid & 63;
    const int m0 = blockIdx.y * 64, n0 = blockIdx.x * 128;
    const int wy = wv >> 1, wx = wv & 1;
    const int lane15 = ln & 15, quad = ln >> 4;

    // stage A: 1024 chunks (64 rows x 16 slots), 4 per thread
#pragma unroll
    for (int i = 0; i < 4; ++i) {
        int c = i * 256 + tid;
        int m = c >> 4, q = c & 15;
        int gq = q ^ (m & 15);
        int arow = m0 + m; if (arow > M - 1) arow = M - 1;
        __builtin_amdgcn_global_load_lds(
            (const __attribute__((address_space(1))) void*)(A + (size_t)arow * 128 + gq * 8),
            (__attribute__((address_space(3))) void*)(As + (i * 4 + wv) * 512), 16, 0, 0);
    }
    // stage B: 2048 chunks (128 rows x 16 slots), 8 per thread
#pragma unroll
    for (int i = 0; i < 8; ++i) {
        int c = i * 256 + tid;
        int n = c >> 4, q = c & 15;
        int gq = q ^ (n & 15);
        __builtin_amdgcn_global_load_lds(
            (const __attribute__((address_space(1))) void*)(Bt + (size_t)(n0 + n) * 128 + gq * 8),
            (__attribute__((address_space(3))) void*)(Bs + (i * 4 + wv) * 512), 16, 0, 0);
    }

    f32x4 acc[2][4];
#pragma unroll
    for (int fy = 0; fy < 2; ++fy)
#pragma unroll
        for (int fx = 0; fx < 4; ++fx)
            acc[fy][fx] = (f32x4)0.0f;

    __syncthreads();                             // the only barrier

#pragma unroll
    for (int kk = 0; kk < 4; ++kk) {             // K = 4 x 32
        short8 af[2], bf[4];
#pragma unroll
        for (int f = 0; f < 2; ++f) {
            int mA = wy * 32 + f * 16 + lane15;
            int sA = (kk * 4 + quad) ^ (mA & 15);
            af[f] = *(const short8*)(As + mA * 128 + sA * 8);
        }
#pragma unroll
        for (int f = 0; f < 4; ++f) {
            int nB = wx * 64 + f * 16 + lane15;
            int sB = (kk * 4 + quad) ^ (nB & 15);
            bf[f] = *(const short8*)(Bs + nB * 128 + sB * 8);
        }
#pragma unroll
        for (int fy = 0; fy < 2; ++fy)
#pragma unroll
            for (int fx = 0; fx < 4; ++fx)
                acc[fy][fx] = __builtin_amdgcn_mfma_f32_16x16x32_bf16(
                    af[fy], bf[fx], acc[fy][fx], 0, 0, 0);
    }

    // epilogue: col=lane&15, row=quad*4+reg
#pragma unroll
    for (int fy = 0; fy < 2; ++fy) {
        int rowb = m0 + wy * 32 + fy * 16 + quad * 4;
#pragma unroll
        for (int fx = 0; fx < 4; ++fx) {
            int col = n0 + wx * 64 + fx * 16 + lane15;
            float bia = bias[col];
            f32x4 v = acc[fy][fx];
#pragma unroll
            for (int r = 0; r < 4; ++r) {
                int row = rowb + r;
                if (row < M)
                    C[(size_t)row * F1 + col] = f2bf(fmaxf(v[r] + bia, 0.0f));
            }
        }
    }
}

// ========== gemm2: K=512 dbuf bf16 MFMA GEMM (+rowscale) ==========
// 64x128 tile, BK=32, double-buffered LDS, post-barrier prefetch.
__global__ __launch_bounds__(256) void k_gemm_bf16(
        const unsigned short* __restrict__ A, int lda,
        const unsigned short* __restrict__ Bt, int ldb,
        unsigned short* __restrict__ C, int ldc,
        const float* __restrict__ rowscale,
        int M, int K)
{
    __shared__ unsigned short As[2][64 * 32];    // 2 x 4 KB
    __shared__ unsigned short Bs[2][128 * 32];   // 2 x 8 KB

    const int tid = threadIdx.x;
    const int wv = tid >> 6, ln = tid & 63;
    const int m0 = blockIdx.y * 64, n0 = blockIdx.x * 128;
    const int wy = wv >> 1, wx = wv & 1;
    const int lane15 = ln & 15, quad = ln >> 4;

    const int cA = tid, mA_ = cA >> 2, qA = cA & 3;
    const int gqA = qA ^ ((mA_ >> 1) & 3);
    int arow = m0 + mA_; if (arow > M - 1) arow = M - 1;
    const unsigned short* agp = A + (size_t)arow * lda + gqA * 8;
    const int aofs = wv * 512;

    const unsigned short* bgp[2];
    int bofs[2];
#pragma unroll
    for (int i = 0; i < 2; ++i) {
        int c = (i * 4 + wv) * 64 + ln;
        int m = c >> 2, q = c & 3;
        int gq = q ^ ((m >> 1) & 3);
        bgp[i] = Bt + (size_t)(n0 + m) * ldb + gq * 8;
        bofs[i] = (i * 4 + wv) * 512;
    }

    f32x4 acc[2][4];
#pragma unroll
    for (int fy = 0; fy < 2; ++fy)
#pragma unroll
        for (int fx = 0; fx < 4; ++fx)
            acc[fy][fx] = (f32x4)0.0f;

    const int NK = K >> 5;

    __builtin_amdgcn_global_load_lds(
        (const __attribute__((address_space(1))) void*)agp,
        (__attribute__((address_space(3))) void*)(&As[0][0] + aofs), 16, 0, 0);
#pragma unroll
    for (int i = 0; i < 2; ++i)
        __builtin_amdgcn_global_load_lds(
            (const __attribute__((address_space(1))) void*)bgp[i],
            (__attribute__((address_space(3))) void*)(&Bs[0][0] + bofs[i]), 16, 0, 0);

    for (int ks = 0; ks < NK; ++ks) {
        __syncthreads();
        if (ks + 1 < NK) {
            int ko = (ks + 1) << 5;
            int nb = (ks + 1) & 1;
            __builtin_amdgcn_global_load_lds(
                (const __attribute__((address_space(1))) void*)(agp + ko),
                (__attribute__((address_space(3))) void*)(&As[nb][0] + aofs), 16, 0, 0);
#pragma unroll
            for (int i = 0; i < 2; ++i)
                __builtin_amdgcn_global_load_lds(
                    (const __attribute__((address_space(1))) void*)(bgp[i] + ko),
                    (__attribute__((address_space(3))) void*)(&Bs[nb][0] + bofs[i]), 16, 0, 0);
        }
        const int b = ks & 1;
        short8 af[2], bf[4];
#pragma unroll
        for (int f = 0; f < 2; ++f) {
            int mA = wy * 32 + f * 16 + lane15;
            int sA = quad ^ ((mA >> 1) & 3);
            af[f] = *(const short8*)(&As[b][0] + mA * 32 + sA * 8);
        }
#pragma unroll
        for (int f = 0; f < 4; ++f) {
            int nB = wx * 64 + f * 16 + lane15;
            int sB = quad ^ ((nB >> 1) & 3);
            bf[f] = *(const short8*)(&Bs[b][0] + nB * 32 + sB * 8);
        }
#pragma unroll
        for (int fy = 0; fy < 2; ++fy)
#pragma unroll
            for (int fx = 0; fx < 4; ++fx)
                acc[fy][fx] = __builtin_amdgcn_mfma_f32_16x16x32_bf16(
                    af[fy], bf[fx], acc[fy][fx], 0, 0, 0);
    }

#pragma unroll
    for (int fy = 0; fy < 2; ++fy) {
        int rowb = m0 + wy * 32 + fy * 16 + quad * 4;
        float rs[4];
#pragma unroll
        for (int r = 0; r < 4; ++r) {
            int row = rowb + r; if (row > M - 1) row = M - 1;
            rs[r] = rowscale[row];
        }
#pragma unroll
        for (int fx = 0; fx < 4; ++fx) {
            int col = n0 + wx * 64 + fx * 16 + lane15;
            f32x4 v = acc[fy][fx];
#pragma unroll
            for (int r = 0; r < 4; ++r) {
                int row = rowb + r;
                if (row < M)
                    C[(size_t)row * ldc + col] = f2bf(v[r] * rs[r]);
            }
        }
    }
}

extern "C" void kernel_launch(void* const* d_in, const int* in_sizes, int n_in,
                              void* d_out, int out_size, void* d_ws, size_t ws_size,
                              hipStream_t stream) {
    const float* x  = (const float*)d_in[0];
    const int*   ei = (const int*)d_in[1];
    const float* W1 = (const float*)d_in[2];
    const float* b1 = (const float*)d_in[3];
    const float* W2 = (const float*)d_in[4];
    const float* b2 = (const float*)d_in[5];
    float* out = (float*)d_out;

    // workspace carve (256 B aligned)
    char* p = (char*)d_ws;
    auto carve = [&](size_t bytes) { char* r = p; p += (bytes + 255) & ~(size_t)255; return r; };
    float*          dinv = (float*)carve(NN * 4);
    int*            cnt  = (int*)carve(SCAN_N * 4);
    int*            off  = (int*)carve((NN + 1) * 4);
    int*            csr  = (int*)carve(NE * 4);
    int*            bsum = (int*)carve(64 * 4);
    int*            boff = (int*)carve(64 * 4);
    unsigned short* xs   = (unsigned short*)carve((size_t)NN * F0 * 2);
    unsigned short* agg1 = (unsigned short*)carve((size_t)NN * F0 * 2);
    unsigned short* h1   = (unsigned short*)carve((size_t)NN * F1 * 2);
    unsigned short* t2s  = (unsigned short*)carve((size_t)NN * 256 * 2);
    unsigned short* w1t  = (unsigned short*)carve((size_t)F1 * F0 * 2);
    unsigned short* w2t  = (unsigned short*)carve((size_t)256 * F1 * 2);

    // CSR + norm
    hipMemsetAsync(cnt, 0, SCAN_N * sizeof(int), stream);
    k_hist <<<(NE / 4 + 255) / 256, 256, 0, stream>>>((const int4*)(ei + NE), cnt);
    k_scanA<<<SCAN_B, 256, 0, stream>>>((const int4*)cnt, bsum);
    k_scanB<<<1, 64, 0, stream>>>(bsum, boff);
    k_scanC<<<SCAN_B, 256, 0, stream>>>((const int4*)cnt, boff, off, dinv);
    k_bucket<<<(NE / 4 + 255) / 256, 256, 0, stream>>>(
        (const int4*)ei, (const int4*)(ei + NE), off, cnt, csr);

    // fused prep: xs = bf16(dinv*x), W1t, W2t
    k_prep<<<6250 + 256 + 512, 256, 0, stream>>>(
        (const float4*)x, dinv, (ushort4*)xs, W1, w1t, W2, w2t);

    // layer 1: aggregate (128-dim) then single-shot MFMA GEMM + bias + relu
    k_gather1<<<(NN + 3) / 4, 256, 0, stream>>>((const unsigned int*)xs, off, csr,
                                                dinv, (unsigned int*)agg1);
    k_gemm1<<<dim3(F1 / 128, MT64), 256, 0, stream>>>(agg1, w1t, h1, b1, NN);

    // layer 2: MFMA GEMM (rowscale=dinv) -> t2s bf16, then gather + bias + relu
    k_gemm_bf16<<<dim3(256 / 128, MT64), 256, 0, stream>>>(
        h1, F1, w2t, F1, t2s, 256, dinv, NN, F1);
    k_gather2<<<(NN + 3) / 4, 256, 0, stream>>>((const ushort4*)t2s, off, csr, dinv,
                                                b2, out);
}